// Round 1
// baseline (635.517 us; speedup 1.0000x reference)
//
#include <hip/hip_runtime.h>
#include <hip/hip_bf16.h>
#include <math.h>

// Problem constants
#define BATCH 32
#define C 256
#define HW 3136           // 56*56
#define NMAT (BATCH * C * C)   // elements in one batched (32,256,256) tensor
#define OUTROW 32896      // C*(C+1)/2

// ---------------------------------------------------------------------------
// 1) per-(b,c) row sums: s[b*C+c] = sum_n x[b,c,n]
// ---------------------------------------------------------------------------
__global__ void k_rowsum(const float* __restrict__ x, float* __restrict__ s) {
    int row = blockIdx.x;                 // b*C + c  (0..8191)
    const float* p = x + (size_t)row * HW;
    float acc = 0.f;
    for (int i = threadIdx.x; i < HW; i += 256) acc += p[i];
    for (int off = 32; off; off >>= 1) acc += __shfl_down(acc, off, 64);
    __shared__ float ls[4];
    if ((threadIdx.x & 63) == 0) ls[threadIdx.x >> 6] = acc;
    __syncthreads();
    if (threadIdx.x == 0) s[row] = ls[0] + ls[1] + ls[2] + ls[3];
}

// ---------------------------------------------------------------------------
// 2) gram[b] = xn[b] @ xn[b]^T   (256x256, K=3136) — 64x64x16 LDS tile,
//    256 threads, 4x4 micro-tile per thread.
// ---------------------------------------------------------------------------
__global__ __launch_bounds__(256) void k_gram(const float* __restrict__ x,
                                              float* __restrict__ g) {
    const int b  = blockIdx.z;
    const int tm = blockIdx.y;            // 0..3 row tile
    const int tn = blockIdx.x;            // 0..3 col tile
    const float* X = x + (size_t)b * C * HW;
    float* G = g + (size_t)b * C * C;

    __shared__ float As[16][64];          // As[k][m]
    __shared__ float Bs[16][64];          // Bs[k][n]

    const int t  = threadIdx.x;
    const int lr = t >> 2;                // 0..63 row within tile (for loads)
    const int lq = t & 3;                 // 0..3  k-quad (for loads)
    const int ty = t >> 4;                // 0..15 (compute row group)
    const int tx = t & 15;                // 0..15 (compute col group)

    float acc[4][4] = {};

    const float* pa = X + (size_t)(tm * 64 + lr) * HW + lq * 4;
    const float* pb = X + (size_t)(tn * 64 + lr) * HW + lq * 4;

    for (int k0 = 0; k0 < HW; k0 += 16) {
        float4 av = *(const float4*)(pa + k0);
        float4 bv = *(const float4*)(pb + k0);
        __syncthreads();
        As[lq * 4 + 0][lr] = av.x;
        As[lq * 4 + 1][lr] = av.y;
        As[lq * 4 + 2][lr] = av.z;
        As[lq * 4 + 3][lr] = av.w;
        Bs[lq * 4 + 0][lr] = bv.x;
        Bs[lq * 4 + 1][lr] = bv.y;
        Bs[lq * 4 + 2][lr] = bv.z;
        Bs[lq * 4 + 3][lr] = bv.w;
        __syncthreads();
#pragma unroll
        for (int k = 0; k < 16; ++k) {
            float4 a4 = *(const float4*)&As[k][ty * 4];
            float4 b4 = *(const float4*)&Bs[k][tx * 4];
            float ar[4] = {a4.x, a4.y, a4.z, a4.w};
            float br[4] = {b4.x, b4.y, b4.z, b4.w};
#pragma unroll
            for (int i = 0; i < 4; ++i)
#pragma unroll
                for (int j = 0; j < 4; ++j) acc[i][j] += ar[i] * br[j];
        }
    }
#pragma unroll
    for (int i = 0; i < 4; ++i) {
        int row = tm * 64 + ty * 4 + i;
        float4 v = make_float4(acc[i][0], acc[i][1], acc[i][2], acc[i][3]);
        *(float4*)&G[(size_t)row * C + tn * 64 + tx * 4] = v;
    }
}

// ---------------------------------------------------------------------------
// 3) trace[b] = tr(gram)/n - sum_i s_i^2 / n^2
// ---------------------------------------------------------------------------
__global__ void k_trace(const float* __restrict__ g, const float* __restrict__ s,
                        float* __restrict__ tr) {
    int b = blockIdx.x;
    int i = threadIdx.x;
    float gd = g[(size_t)b * C * C + (size_t)i * (C + 1)];
    float sv = s[b * C + i];
    const float n = (float)HW;
    float v = gd / n - (sv * sv) / (n * n);
    for (int off = 32; off; off >>= 1) v += __shfl_down(v, off, 64);
    __shared__ float red[4];
    if ((i & 63) == 0) red[i >> 6] = v;
    __syncthreads();
    if (i == 0) tr[b] = red[0] + red[1] + red[2] + red[3];
}

// ---------------------------------------------------------------------------
// 4) a = (gram/n - s_i s_j / n^2) / trace[b]
// ---------------------------------------------------------------------------
__global__ void k_make_a(const float* __restrict__ g, const float* __restrict__ s,
                         const float* __restrict__ tr, float* __restrict__ a) {
    int b = blockIdx.y;
    int i = blockIdx.x;
    int j = threadIdx.x;
    const float n = (float)HW;
    size_t idx = (size_t)b * C * C + (size_t)i * C + j;
    float sigma = g[idx] / n - (s[b * C + i] * s[b * C + j]) / (n * n);
    a[idx] = sigma / tr[b];
}

// ---------------------------------------------------------------------------
// 5) z0 = 1.5*I - 0.5*a   (elementwise)
// ---------------------------------------------------------------------------
__global__ void k_z0(const float* __restrict__ a, float* __restrict__ z) {
    int b = blockIdx.y;
    int i = blockIdx.x;
    int j = threadIdx.x;
    size_t idx = (size_t)b * C * C + (size_t)i * C + j;
    float d = (i == j) ? 1.5f : 0.f;
    z[idx] = d - 0.5f * a[idx];
}

// ---------------------------------------------------------------------------
// 6) batched 256x256x256 matmul.  mode 0: Cm = A@B ; mode 1: Cm = 1.5I - 0.5*(A@B)
// ---------------------------------------------------------------------------
__global__ __launch_bounds__(256) void k_mm(const float* __restrict__ A,
                                            const float* __restrict__ B,
                                            float* __restrict__ Cm, int mode) {
    const int b  = blockIdx.z;
    const int tm = blockIdx.y;            // 0..3
    const int tn = blockIdx.x;            // 0..3
    const float* Ab = A + (size_t)b * C * C;
    const float* Bb = B + (size_t)b * C * C;
    float* Cb = Cm + (size_t)b * C * C;

    __shared__ float As[16][64];          // As[k][m]
    __shared__ float Bs[16][64];          // Bs[k][n]

    const int t  = threadIdx.x;
    const int lr = t >> 2;                // 0..63
    const int lq = t & 3;                 // 0..3
    const int kk = t >> 4;                // 0..15 (B load row)
    const int nq = t & 15;                // 0..15 (B load col quad)
    const int ty = t >> 4;
    const int tx = t & 15;

    float acc[4][4] = {};

    for (int k0 = 0; k0 < C; k0 += 16) {
        float4 av = *(const float4*)(Ab + (size_t)(tm * 64 + lr) * C + k0 + lq * 4);
        float4 bv = *(const float4*)(Bb + (size_t)(k0 + kk) * C + tn * 64 + nq * 4);
        __syncthreads();
        As[lq * 4 + 0][lr] = av.x;
        As[lq * 4 + 1][lr] = av.y;
        As[lq * 4 + 2][lr] = av.z;
        As[lq * 4 + 3][lr] = av.w;
        *(float4*)&Bs[kk][nq * 4] = bv;
        __syncthreads();
#pragma unroll
        for (int k = 0; k < 16; ++k) {
            float4 a4 = *(const float4*)&As[k][ty * 4];
            float4 b4 = *(const float4*)&Bs[k][tx * 4];
            float ar[4] = {a4.x, a4.y, a4.z, a4.w};
            float br[4] = {b4.x, b4.y, b4.z, b4.w};
#pragma unroll
            for (int i = 0; i < 4; ++i)
#pragma unroll
                for (int j = 0; j < 4; ++j) acc[i][j] += ar[i] * br[j];
        }
    }
#pragma unroll
    for (int i = 0; i < 4; ++i) {
        int row = tm * 64 + ty * 4 + i;
        int col = tn * 64 + tx * 4;
        float4 v;
        if (mode == 0) {
            v = make_float4(acc[i][0], acc[i][1], acc[i][2], acc[i][3]);
        } else {
            float d0 = (row == col + 0) ? 1.5f : 0.f;
            float d1 = (row == col + 1) ? 1.5f : 0.f;
            float d2 = (row == col + 2) ? 1.5f : 0.f;
            float d3 = (row == col + 3) ? 1.5f : 0.f;
            v = make_float4(d0 - 0.5f * acc[i][0], d1 - 0.5f * acc[i][1],
                            d2 - 0.5f * acc[i][2], d3 - 0.5f * acc[i][3]);
        }
        *(float4*)&Cb[(size_t)row * C + col] = v;
    }
}

// ---------------------------------------------------------------------------
// 7) triuvec with sqrt(trace) scaling
// ---------------------------------------------------------------------------
__global__ void k_triuvec(const float* __restrict__ y, const float* __restrict__ tr,
                          float* __restrict__ out) {
    int b = blockIdx.y;
    int r = blockIdx.x;
    int j = threadIdx.x;
    float sc = sqrtf(tr[b]);
    if (j >= r) {
        int base = r * C - (r * (r - 1)) / 2;   // sum_{i<r} (C - i)
        out[(size_t)b * OUTROW + base + (j - r)] =
            y[(size_t)b * C * C + (size_t)r * C + j] * sc;
    }
}

// ---------------------------------------------------------------------------
extern "C" void kernel_launch(void* const* d_in, const int* in_sizes, int n_in,
                              void* d_out, int out_size, void* d_ws, size_t ws_size,
                              hipStream_t stream) {
    const float* x = (const float*)d_in[0];
    float* out = (float*)d_out;
    float* ws = (float*)d_ws;

    // 5 ping-pong matrices + small buffers (~42 MB total)
    float* P0 = ws;
    float* P1 = P0 + NMAT;
    float* P2 = P1 + NMAT;
    float* P3 = P2 + NMAT;
    float* P4 = P3 + NMAT;
    float* sbuf  = P4 + NMAT;        // 8192 floats
    float* trbuf = sbuf + BATCH * C; // 32 floats

    k_rowsum<<<dim3(BATCH * C), 256, 0, stream>>>(x, sbuf);
    k_gram<<<dim3(4, 4, BATCH), 256, 0, stream>>>(x, P0);
    k_trace<<<dim3(BATCH), 256, 0, stream>>>(P0, sbuf, trbuf);
    k_make_a<<<dim3(C, BATCH), 256, 0, stream>>>(P0, sbuf, trbuf, P1);   // a -> P1
    k_z0<<<dim3(C, BATCH), 256, 0, stream>>>(P1, P0);                    // Z0 -> P0
    k_mm<<<dim3(4, 4, BATCH), 256, 0, stream>>>(P1, P0, P2, 0);          // Y0 = a@Z0 -> P2

    float* y = P2;
    float* z = P0;
    float* f0 = P1;
    float* f1 = P3;
    float* f2 = P4;
    for (int it = 0; it < 4; ++it) {
        float* T  = f0;
        k_mm<<<dim3(4, 4, BATCH), 256, 0, stream>>>(z, y, T, 1);   // T = 1.5I - 0.5 z@y
        float* yn = f1;
        float* zn = f2;
        k_mm<<<dim3(4, 4, BATCH), 256, 0, stream>>>(y, T, yn, 0);  // y' = y@T
        k_mm<<<dim3(4, 4, BATCH), 256, 0, stream>>>(T, z, zn, 0);  // z' = T@z
        f0 = y; f1 = z; f2 = T;
        y = yn; z = zn;
    }

    k_triuvec<<<dim3(C, BATCH), 256, 0, stream>>>(y, trbuf, out);
}

// Round 2
// 534.577 us; speedup vs baseline: 1.1888x; 1.1888x over previous
//
#include <hip/hip_runtime.h>
#include <hip/hip_bf16.h>
#include <math.h>

#define BATCH 32
#define C 256
#define HW 3136
#define OUTROW 32896

typedef __bf16 b8v __attribute__((ext_vector_type(8)));
typedef float  f4v __attribute__((ext_vector_type(4)));

__device__ __forceinline__ unsigned short f2bf(float f) {
    union { float f; unsigned u; } v; v.f = f;
    unsigned r = v.u + 0x7FFFu + ((v.u >> 16) & 1u);
    return (unsigned short)(r >> 16);
}
__device__ __forceinline__ float bf2f(unsigned short h) {
    union { unsigned u; float f; } v; v.u = ((unsigned)h) << 16; return v.f;
}
__device__ __forceinline__ void split2(float x, unsigned short& h, unsigned short& l) {
    h = f2bf(x);
    l = f2bf(x - bf2f(h));
}

// async global->LDS, 16 B per lane; LDS dest = wave-uniform base + lane*16
__device__ __forceinline__ void stage16(const unsigned short* g, unsigned short* l) {
    __builtin_amdgcn_global_load_lds(
        (const __attribute__((address_space(1))) unsigned int*)g,
        (__attribute__((address_space(3))) unsigned int*)l,
        16, 0, 0);
}

__device__ __forceinline__ float wave_sum(float v) {
    for (int o = 32; o; o >>= 1) v += __shfl_down(v, o, 64);
    return v;
}

// ---------------------------------------------------------------------------
// prep: x (fp32) -> x_hi, x_lo (bf16 split); per-row sum and sum-of-squares
// ---------------------------------------------------------------------------
__global__ void k_prep(const float* __restrict__ x, unsigned short* __restrict__ xh,
                       unsigned short* __restrict__ xl, float* __restrict__ sbuf,
                       float* __restrict__ qbuf) {
    const int row = blockIdx.x;                      // b*C + c
    const float4* xr = (const float4*)(x + (size_t)row * HW);
    ushort4* hr = (ushort4*)(xh + (size_t)row * HW);
    ushort4* lr = (ushort4*)(xl + (size_t)row * HW);
    float s = 0.f, q = 0.f;
    for (int c = threadIdx.x; c < HW / 4; c += 256) {
        float4 v = xr[c];
        ushort4 h, l;
        split2(v.x, h.x, l.x); split2(v.y, h.y, l.y);
        split2(v.z, h.z, l.z); split2(v.w, h.w, l.w);
        hr[c] = h; lr[c] = l;
        s += v.x + v.y + v.z + v.w;
        q += v.x * v.x + v.y * v.y + v.z * v.z + v.w * v.w;
    }
    s = wave_sum(s); q = wave_sum(q);
    __shared__ float ss[4], qq[4];
    if ((threadIdx.x & 63) == 0) { ss[threadIdx.x >> 6] = s; qq[threadIdx.x >> 6] = q; }
    __syncthreads();
    if (threadIdx.x == 0) {
        sbuf[row] = ss[0] + ss[1] + ss[2] + ss[3];
        qbuf[row] = qq[0] + qq[1] + qq[2] + qq[3];
    }
}

// ---------------------------------------------------------------------------
// trace: tr[b] = sum_c q/n - s^2/n^2 ; also sqrt(tr)
// ---------------------------------------------------------------------------
__global__ void k_tr(const float* __restrict__ sbuf, const float* __restrict__ qbuf,
                     float* __restrict__ trbuf, float* __restrict__ strbuf) {
    const int b = blockIdx.x, t = threadIdx.x;
    const float invn = 1.f / (float)HW, invn2 = invn * invn;
    float sv = sbuf[b * C + t];
    float v = qbuf[b * C + t] * invn - sv * sv * invn2;
    v = wave_sum(v);
    __shared__ float red[4];
    if ((t & 63) == 0) red[t >> 6] = v;
    __syncthreads();
    if (t == 0) {
        float tr = red[0] + red[1] + red[2] + red[3];
        trbuf[b] = tr;
        strbuf[b] = sqrtf(tr);
    }
}

// ---------------------------------------------------------------------------
// MFMA GEMM: Cacc[m][n] = sum_k A[m,k]*B[n,k]  (A·B^T; all operands symmetric
// or gram-shaped so row reads suffice).  Split-bf16: hi*hi + hi*lo + lo*hi.
// Block: 256 thr = 4 waves, 64x64 tile, wave-tile 32x32 (2x2 of 16x16x32).
// Grid: (10 upper tile-pairs, batch). Mirrors writes to lower triangle.
// MODE 0: D = acc               -> Dh/Dl
// MODE 1: D = 1.5I - 0.5*acc    -> Dh/Dl
// MODE 2: out = triuvec(acc * sqrt(tr))
// MODE 3: gram epilogue: a = (acc/n - s_i s_j/n^2)/tr -> Dh/Dl ;
//         z0 = 1.5I - 0.5a -> D2h/D2l
// ---------------------------------------------------------------------------
template <int MODE>
__global__ __launch_bounds__(256) void k_gemm(
    const unsigned short* __restrict__ Ah, const unsigned short* __restrict__ Al,
    const unsigned short* __restrict__ Bh, const unsigned short* __restrict__ Bl,
    int K,
    unsigned short* __restrict__ Dh, unsigned short* __restrict__ Dl,
    unsigned short* __restrict__ D2h, unsigned short* __restrict__ D2l,
    float* __restrict__ outF,
    const float* __restrict__ sbuf, const float* __restrict__ trbuf,
    const float* __restrict__ strbuf) {
    const int b = blockIdx.y;
    int p = blockIdx.x, tm = 0, rem = 4;
    while (p >= rem) { p -= rem; ++tm; --rem; }
    const int tn = tm + p;

    const int tid = threadIdx.x, wave = tid >> 6, lane = tid & 63;
    const int wr = wave >> 1, wc = wave & 1;

    __shared__ __align__(16) unsigned short lds[4][2048];  // 4 bufs x [q(4)][m(64)][8]

    const size_t matAB = (size_t)b * C * (size_t)K;
    const unsigned short* src;
    {
        const unsigned short* s0 = (wave == 0) ? Ah : (wave == 1) ? Al : (wave == 2) ? Bh : Bl;
        const int r0 = (wave < 2) ? tm * 64 : tn * 64;
        src = s0 + matAB + (size_t)(r0 + lane) * K;
    }
    unsigned short* lbuf = &lds[wave][0];

    f4v acc[2][2] = {};

    const int q = lane >> 4, r = lane & 15;
    const int mA0 = q * 512 + (wr * 32 + r) * 8;   // rt=0 ; rt=1 at +128
    const int nB0 = q * 512 + (wc * 32 + r) * 8;   // ct=0 ; ct=1 at +128

    for (int k0 = 0; k0 < K; k0 += 32) {
        __syncthreads();
#pragma unroll
        for (int c = 0; c < 4; ++c) stage16(src + k0 + c * 8, lbuf + c * 512);
        __syncthreads();
        b8v ah0 = *(const b8v*)&lds[0][mA0];
        b8v ah1 = *(const b8v*)&lds[0][mA0 + 128];
        b8v al0 = *(const b8v*)&lds[1][mA0];
        b8v al1 = *(const b8v*)&lds[1][mA0 + 128];
        b8v bh0 = *(const b8v*)&lds[2][nB0];
        b8v bh1 = *(const b8v*)&lds[2][nB0 + 128];
        b8v bl0 = *(const b8v*)&lds[3][nB0];
        b8v bl1 = *(const b8v*)&lds[3][nB0 + 128];

        acc[0][0] = __builtin_amdgcn_mfma_f32_16x16x32_bf16(ah0, bh0, acc[0][0], 0, 0, 0);
        acc[0][0] = __builtin_amdgcn_mfma_f32_16x16x32_bf16(ah0, bl0, acc[0][0], 0, 0, 0);
        acc[0][0] = __builtin_amdgcn_mfma_f32_16x16x32_bf16(al0, bh0, acc[0][0], 0, 0, 0);

        acc[0][1] = __builtin_amdgcn_mfma_f32_16x16x32_bf16(ah0, bh1, acc[0][1], 0, 0, 0);
        acc[0][1] = __builtin_amdgcn_mfma_f32_16x16x32_bf16(ah0, bl1, acc[0][1], 0, 0, 0);
        acc[0][1] = __builtin_amdgcn_mfma_f32_16x16x32_bf16(al0, bh1, acc[0][1], 0, 0, 0);

        acc[1][0] = __builtin_amdgcn_mfma_f32_16x16x32_bf16(ah1, bh0, acc[1][0], 0, 0, 0);
        acc[1][0] = __builtin_amdgcn_mfma_f32_16x16x32_bf16(ah1, bl0, acc[1][0], 0, 0, 0);
        acc[1][0] = __builtin_amdgcn_mfma_f32_16x16x32_bf16(al1, bh0, acc[1][0], 0, 0, 0);

        acc[1][1] = __builtin_amdgcn_mfma_f32_16x16x32_bf16(ah1, bh1, acc[1][1], 0, 0, 0);
        acc[1][1] = __builtin_amdgcn_mfma_f32_16x16x32_bf16(ah1, bl1, acc[1][1], 0, 0, 0);
        acc[1][1] = __builtin_amdgcn_mfma_f32_16x16x32_bf16(al1, bh1, acc[1][1], 0, 0, 0);
    }

    // epilogue
    const size_t dmat = (size_t)b * C * C;
    const float invn = 1.f / (float)HW, invn2 = invn * invn;
    float tr = 1.f, str = 1.f;
    if (MODE == 3) tr = trbuf[b];
    if (MODE == 2) str = strbuf[b];

#pragma unroll
    for (int rt = 0; rt < 2; ++rt) {
#pragma unroll
        for (int ct = 0; ct < 2; ++ct) {
            const int j = tn * 64 + wc * 32 + ct * 16 + r;
#pragma unroll
            for (int reg = 0; reg < 4; ++reg) {
                const int i = tm * 64 + wr * 32 + rt * 16 + q * 4 + reg;
                float v = acc[rt][ct][reg];
                if (MODE == 3) {
                    float si = sbuf[b * C + i], sj = sbuf[b * C + j];
                    float av = (v * invn - si * sj * invn2) / tr;
                    unsigned short h, l;
                    split2(av, h, l);
                    Dh[dmat + (size_t)i * C + j] = h; Dl[dmat + (size_t)i * C + j] = l;
                    Dh[dmat + (size_t)j * C + i] = h; Dl[dmat + (size_t)j * C + i] = l;
                    float zv = ((i == j) ? 1.5f : 0.f) - 0.5f * av;
                    split2(zv, h, l);
                    D2h[dmat + (size_t)i * C + j] = h; D2l[dmat + (size_t)i * C + j] = l;
                    D2h[dmat + (size_t)j * C + i] = h; D2l[dmat + (size_t)j * C + i] = l;
                } else if (MODE == 2) {
                    if (j >= i)
                        outF[(size_t)b * OUTROW + (size_t)(i * C - (i * (i - 1)) / 2) + (j - i)] =
                            v * str;
                } else {
                    float d = (MODE == 1) ? (((i == j) ? 1.5f : 0.f) - 0.5f * v) : v;
                    unsigned short h, l;
                    split2(d, h, l);
                    Dh[dmat + (size_t)i * C + j] = h; Dl[dmat + (size_t)i * C + j] = l;
                    Dh[dmat + (size_t)j * C + i] = h; Dl[dmat + (size_t)j * C + i] = l;
                }
            }
        }
    }
}

// ---------------------------------------------------------------------------
extern "C" void kernel_launch(void* const* d_in, const int* in_sizes, int n_in,
                              void* d_out, int out_size, void* d_ws, size_t ws_size,
                              hipStream_t stream) {
    const float* x = (const float*)d_in[0];
    float* out = (float*)d_out;

    unsigned short* W = (unsigned short*)d_ws;
    const size_t XN = (size_t)BATCH * C * HW;     // 25,690,112
    const size_t M = (size_t)BATCH * C * C;       //  2,097,152
    unsigned short* XH = W;
    unsigned short* XL = XH + XN;
    unsigned short* P = XL + XN;
    // 4 symmetric-matrix pairs (hi,lo)
    unsigned short* PA_h = P + 0 * M; unsigned short* PA_l = P + 1 * M;
    unsigned short* PB_h = P + 2 * M; unsigned short* PB_l = P + 3 * M;
    unsigned short* PC_h = P + 4 * M; unsigned short* PC_l = P + 5 * M;
    unsigned short* PD_h = P + 6 * M; unsigned short* PD_l = P + 7 * M;
    float* F = (float*)(P + 8 * M);
    float* sbuf = F;                 // 8192
    float* qbuf = sbuf + BATCH * C;  // 8192
    float* trbuf = qbuf + BATCH * C; // 32
    float* strbuf = trbuf + BATCH;   // 32

    k_prep<<<dim3(BATCH * C), 256, 0, stream>>>(x, XH, XL, sbuf, qbuf);
    k_tr<<<dim3(BATCH), 256, 0, stream>>>(sbuf, qbuf, trbuf, strbuf);

    dim3 g(10, BATCH);
    // gram -> a (A pair), z0 (B pair)
    k_gemm<3><<<g, 256, 0, stream>>>(XH, XL, XH, XL, HW, PA_h, PA_l, PB_h, PB_l,
                                     nullptr, sbuf, trbuf, strbuf);
    // Y0 = a @ z0 -> C
    k_gemm<0><<<g, 256, 0, stream>>>(PA_h, PA_l, PB_h, PB_l, C, PC_h, PC_l,
                                     nullptr, nullptr, nullptr, sbuf, trbuf, strbuf);
    // it0: T = z@y = B@C -> D ; Y1 = C@D -> A ; Z1 = D@B -> C
    k_gemm<1><<<g, 256, 0, stream>>>(PB_h, PB_l, PC_h, PC_l, C, PD_h, PD_l,
                                     nullptr, nullptr, nullptr, sbuf, trbuf, strbuf);
    k_gemm<0><<<g, 256, 0, stream>>>(PC_h, PC_l, PD_h, PD_l, C, PA_h, PA_l,
                                     nullptr, nullptr, nullptr, sbuf, trbuf, strbuf);
    k_gemm<0><<<g, 256, 0, stream>>>(PD_h, PD_l, PB_h, PB_l, C, PC_h, PC_l,
                                     nullptr, nullptr, nullptr, sbuf, trbuf, strbuf);
    // it1: T = C@A -> B ; Y2 = A@B -> D ; Z2 = B@C -> A
    k_gemm<1><<<g, 256, 0, stream>>>(PC_h, PC_l, PA_h, PA_l, C, PB_h, PB_l,
                                     nullptr, nullptr, nullptr, sbuf, trbuf, strbuf);
    k_gemm<0><<<g, 256, 0, stream>>>(PA_h, PA_l, PB_h, PB_l, C, PD_h, PD_l,
                                     nullptr, nullptr, nullptr, sbuf, trbuf, strbuf);
    k_gemm<0><<<g, 256, 0, stream>>>(PB_h, PB_l, PC_h, PC_l, C, PA_h, PA_l,
                                     nullptr, nullptr, nullptr, sbuf, trbuf, strbuf);
    // it2: T = A@D -> C ; Y3 = D@C -> B ; Z3 = C@A -> D
    k_gemm<1><<<g, 256, 0, stream>>>(PA_h, PA_l, PD_h, PD_l, C, PC_h, PC_l,
                                     nullptr, nullptr, nullptr, sbuf, trbuf, strbuf);
    k_gemm<0><<<g, 256, 0, stream>>>(PD_h, PD_l, PC_h, PC_l, C, PB_h, PB_l,
                                     nullptr, nullptr, nullptr, sbuf, trbuf, strbuf);
    k_gemm<0><<<g, 256, 0, stream>>>(PC_h, PC_l, PA_h, PA_l, C, PD_h, PD_l,
                                     nullptr, nullptr, nullptr, sbuf, trbuf, strbuf);
    // it3: T = D@B -> A ; final out = triuvec((B@A) * sqrt(tr))
    k_gemm<1><<<g, 256, 0, stream>>>(PD_h, PD_l, PB_h, PB_l, C, PA_h, PA_l,
                                     nullptr, nullptr, nullptr, sbuf, trbuf, strbuf);
    k_gemm<2><<<g, 256, 0, stream>>>(PB_h, PB_l, PA_h, PA_l, C, nullptr, nullptr,
                                     nullptr, nullptr, out, sbuf, trbuf, strbuf);
}

// Round 3
// 516.810 us; speedup vs baseline: 1.2297x; 1.0344x over previous
//
#include <hip/hip_runtime.h>
#include <hip/hip_bf16.h>
#include <math.h>

#define BATCH 32
#define C 256
#define HW 3136
#define OUTROW 32896
#define KSPLIT 7
#define KCHUNK 448   // HW / KSPLIT, multiple of 32

typedef __bf16 b8v __attribute__((ext_vector_type(8)));
typedef float  f4v __attribute__((ext_vector_type(4)));

__device__ __forceinline__ unsigned short f2bf(float f) {
    union { float f; unsigned u; } v; v.f = f;
    unsigned r = v.u + 0x7FFFu + ((v.u >> 16) & 1u);
    return (unsigned short)(r >> 16);
}
__device__ __forceinline__ float bf2f(unsigned short h) {
    union { unsigned u; float f; } v; v.u = ((unsigned)h) << 16; return v.f;
}
__device__ __forceinline__ void split2(float x, unsigned short& h, unsigned short& l) {
    h = f2bf(x);
    l = f2bf(x - bf2f(h));
}

__device__ __forceinline__ void stage16(const unsigned short* g, unsigned short* l) {
    __builtin_amdgcn_global_load_lds(
        (const __attribute__((address_space(1))) unsigned int*)g,
        (__attribute__((address_space(3))) unsigned int*)l,
        16, 0, 0);
}

__device__ __forceinline__ float wave_sum(float v) {
    for (int o = 32; o; o >>= 1) v += __shfl_down(v, o, 64);
    return v;
}

// ---------------------------------------------------------------------------
// prep: x -> hi/lo bf16 split, per-row sum and sum-of-squares
// ---------------------------------------------------------------------------
__global__ void k_prep(const float* __restrict__ x, unsigned short* __restrict__ xh,
                       unsigned short* __restrict__ xl, float* __restrict__ sbuf,
                       float* __restrict__ qbuf) {
    const int row = blockIdx.x;
    const float4* xr = (const float4*)(x + (size_t)row * HW);
    ushort4* hr = (ushort4*)(xh + (size_t)row * HW);
    ushort4* lr = (ushort4*)(xl + (size_t)row * HW);
    float s = 0.f, q = 0.f;
    for (int c = threadIdx.x; c < HW / 4; c += 256) {
        float4 v = xr[c];
        ushort4 h, l;
        split2(v.x, h.x, l.x); split2(v.y, h.y, l.y);
        split2(v.z, h.z, l.z); split2(v.w, h.w, l.w);
        hr[c] = h; lr[c] = l;
        s += v.x + v.y + v.z + v.w;
        q += v.x * v.x + v.y * v.y + v.z * v.z + v.w * v.w;
    }
    s = wave_sum(s); q = wave_sum(q);
    __shared__ float ss[4], qq[4];
    if ((threadIdx.x & 63) == 0) { ss[threadIdx.x >> 6] = s; qq[threadIdx.x >> 6] = q; }
    __syncthreads();
    if (threadIdx.x == 0) {
        sbuf[row] = ss[0] + ss[1] + ss[2] + ss[3];
        qbuf[row] = qq[0] + qq[1] + qq[2] + qq[3];
    }
}

__global__ void k_tr(const float* __restrict__ sbuf, const float* __restrict__ qbuf,
                     float* __restrict__ trbuf, float* __restrict__ strbuf) {
    const int b = blockIdx.x, t = threadIdx.x;
    const float invn = 1.f / (float)HW, invn2 = invn * invn;
    float sv = sbuf[b * C + t];
    float v = qbuf[b * C + t] * invn - sv * sv * invn2;
    v = wave_sum(v);
    __shared__ float red[4];
    if ((t & 63) == 0) red[t >> 6] = v;
    __syncthreads();
    if (t == 0) {
        float tr = red[0] + red[1] + red[2] + red[3];
        trbuf[b] = tr;
        strbuf[b] = sqrtf(tr);
    }
}

// ---------------------------------------------------------------------------
// gram split-K: grid (10 pairs, 32 batch, 7 splits); 64x64 tile, 4 waves,
// fp32 partial tile out.
// ---------------------------------------------------------------------------
__global__ __launch_bounds__(256) void k_gram_split(
    const unsigned short* __restrict__ Xh, const unsigned short* __restrict__ Xl,
    float* __restrict__ part) {
    const int b = blockIdx.y, z = blockIdx.z;
    int p = blockIdx.x, tm = 0, rem = 4;
    while (p >= rem) { p -= rem; ++tm; --rem; }
    const int tn = tm + p;

    const int tid = threadIdx.x, wave = tid >> 6, lane = tid & 63;
    const int wr = wave >> 1, wc = wave & 1;

    __shared__ __align__(16) unsigned short lds[4][2048];  // [q(4)][m(64)][8]

    const size_t matAB = (size_t)b * C * (size_t)HW;
    const unsigned short* src;
    {
        const unsigned short* s0 = (wave == 0) ? Xh : (wave == 1) ? Xl : (wave == 2) ? Xh : Xl;
        const int r0 = (wave < 2) ? tm * 64 : tn * 64;
        src = s0 + matAB + (size_t)(r0 + lane) * HW + z * KCHUNK;
    }
    unsigned short* lbuf = &lds[wave][0];

    f4v acc[2][2] = {};
    const int q = lane >> 4, r = lane & 15;
    const int mA0 = q * 512 + (wr * 32 + r) * 8;
    const int nB0 = q * 512 + (wc * 32 + r) * 8;

    for (int k0 = 0; k0 < KCHUNK; k0 += 32) {
        __syncthreads();
#pragma unroll
        for (int c = 0; c < 4; ++c) stage16(src + k0 + c * 8, lbuf + c * 512);
        __syncthreads();
        b8v ah0 = *(const b8v*)&lds[0][mA0];
        b8v ah1 = *(const b8v*)&lds[0][mA0 + 128];
        b8v al0 = *(const b8v*)&lds[1][mA0];
        b8v al1 = *(const b8v*)&lds[1][mA0 + 128];
        b8v bh0 = *(const b8v*)&lds[2][nB0];
        b8v bh1 = *(const b8v*)&lds[2][nB0 + 128];
        b8v bl0 = *(const b8v*)&lds[3][nB0];
        b8v bl1 = *(const b8v*)&lds[3][nB0 + 128];

        acc[0][0] = __builtin_amdgcn_mfma_f32_16x16x32_bf16(ah0, bh0, acc[0][0], 0, 0, 0);
        acc[0][0] = __builtin_amdgcn_mfma_f32_16x16x32_bf16(ah0, bl0, acc[0][0], 0, 0, 0);
        acc[0][0] = __builtin_amdgcn_mfma_f32_16x16x32_bf16(al0, bh0, acc[0][0], 0, 0, 0);
        acc[0][1] = __builtin_amdgcn_mfma_f32_16x16x32_bf16(ah0, bh1, acc[0][1], 0, 0, 0);
        acc[0][1] = __builtin_amdgcn_mfma_f32_16x16x32_bf16(ah0, bl1, acc[0][1], 0, 0, 0);
        acc[0][1] = __builtin_amdgcn_mfma_f32_16x16x32_bf16(al0, bh1, acc[0][1], 0, 0, 0);
        acc[1][0] = __builtin_amdgcn_mfma_f32_16x16x32_bf16(ah1, bh0, acc[1][0], 0, 0, 0);
        acc[1][0] = __builtin_amdgcn_mfma_f32_16x16x32_bf16(ah1, bl0, acc[1][0], 0, 0, 0);
        acc[1][0] = __builtin_amdgcn_mfma_f32_16x16x32_bf16(al1, bh0, acc[1][0], 0, 0, 0);
        acc[1][1] = __builtin_amdgcn_mfma_f32_16x16x32_bf16(ah1, bh1, acc[1][1], 0, 0, 0);
        acc[1][1] = __builtin_amdgcn_mfma_f32_16x16x32_bf16(ah1, bl1, acc[1][1], 0, 0, 0);
        acc[1][1] = __builtin_amdgcn_mfma_f32_16x16x32_bf16(al1, bh1, acc[1][1], 0, 0, 0);
    }

    float* pt = part + (((size_t)blockIdx.x * BATCH + b) * KSPLIT + z) * 4096;
#pragma unroll
    for (int rt = 0; rt < 2; ++rt)
#pragma unroll
        for (int ct = 0; ct < 2; ++ct)
#pragma unroll
            for (int reg = 0; reg < 4; ++reg) {
                int row = wr * 32 + rt * 16 + q * 4 + reg;
                int col = wc * 32 + ct * 16 + r;
                pt[row * 64 + col] = acc[rt][ct][reg];
            }
}

// ---------------------------------------------------------------------------
// reduce partials -> a (Ahh/All) and z0 (Zhh/Zll), mirrored via LDS transpose
// ---------------------------------------------------------------------------
__global__ __launch_bounds__(256) void k_reduce(
    const float* __restrict__ part, const float* __restrict__ sbuf,
    const float* __restrict__ trbuf,
    unsigned short* __restrict__ Ahh, unsigned short* __restrict__ All,
    unsigned short* __restrict__ Zhh, unsigned short* __restrict__ Zll) {
    const int b = blockIdx.y;
    int p = blockIdx.x, tm = 0, rem = 4;
    while (p >= rem) { p -= rem; ++tm; --rem; }
    const int tn = tm + p;

    const float* pb = part + ((size_t)blockIdx.x * BATCH + b) * KSPLIT * 4096;
    const int t = threadIdx.x;
    const int row = t >> 2, c0 = (t & 3) * 16;

    float s[16];
#pragma unroll
    for (int u = 0; u < 16; ++u) s[u] = 0.f;
    for (int sp = 0; sp < KSPLIT; ++sp) {
        const float* q4 = pb + sp * 4096 + row * 64 + c0;
#pragma unroll
        for (int u4 = 0; u4 < 4; ++u4) {
            float4 v = *(const float4*)(q4 + u4 * 4);
            s[u4 * 4 + 0] += v.x; s[u4 * 4 + 1] += v.y;
            s[u4 * 4 + 2] += v.z; s[u4 * 4 + 3] += v.w;
        }
    }

    const float invn = 1.f / (float)HW, invn2 = invn * invn;
    const float tr = trbuf[b];
    const int gi = tm * 64 + row;
    const float si = sbuf[b * C + gi];
    const size_t mo = (size_t)b * C * C;

    __shared__ unsigned short tAh[64][66], tAl[64][66], tZh[64][66], tZl[64][66];
    unsigned short vAh[16], vAl[16], vZh[16], vZl[16];
#pragma unroll
    for (int u = 0; u < 16; ++u) {
        int gj = tn * 64 + c0 + u;
        float sj = sbuf[b * C + gj];
        float a = (s[u] * invn - si * sj * invn2) / tr;
        split2(a, vAh[u], vAl[u]);
        float zv = ((gi == gj) ? 1.5f : 0.f) - 0.5f * a;
        split2(zv, vZh[u], vZl[u]);
        tAh[row][c0 + u] = vAh[u]; tAl[row][c0 + u] = vAl[u];
        tZh[row][c0 + u] = vZh[u]; tZl[row][c0 + u] = vZl[u];
    }
    size_t off = mo + (size_t)gi * C + tn * 64 + c0;
#pragma unroll
    for (int u4 = 0; u4 < 4; ++u4) {
        *(ushort4*)&Ahh[off + u4 * 4] = *(ushort4*)&vAh[u4 * 4];
        *(ushort4*)&All[off + u4 * 4] = *(ushort4*)&vAl[u4 * 4];
        *(ushort4*)&Zhh[off + u4 * 4] = *(ushort4*)&vZh[u4 * 4];
        *(ushort4*)&Zll[off + u4 * 4] = *(ushort4*)&vZl[u4 * 4];
    }
    if (tm != tn) {
        __syncthreads();
        const int mr = t >> 2, mc0 = (t & 3) * 16;
        size_t moff = mo + (size_t)(tn * 64 + mr) * C + tm * 64 + mc0;
        unsigned short wAh[16], wAl[16], wZh[16], wZl[16];
#pragma unroll
        for (int u = 0; u < 16; ++u) {
            wAh[u] = tAh[mc0 + u][mr]; wAl[u] = tAl[mc0 + u][mr];
            wZh[u] = tZh[mc0 + u][mr]; wZl[u] = tZl[mc0 + u][mr];
        }
#pragma unroll
        for (int u4 = 0; u4 < 4; ++u4) {
            *(ushort4*)&Ahh[moff + u4 * 4] = *(ushort4*)&wAh[u4 * 4];
            *(ushort4*)&All[moff + u4 * 4] = *(ushort4*)&wAl[u4 * 4];
            *(ushort4*)&Zhh[moff + u4 * 4] = *(ushort4*)&wZh[u4 * 4];
            *(ushort4*)&Zll[moff + u4 * 4] = *(ushort4*)&wZl[u4 * 4];
        }
    }
}

// ---------------------------------------------------------------------------
// per-wave 32x32 GEMM core, K=256, no barriers (per-wave LDS slice)
// LDS layout per array: [q(4)][row(32)][8] = 1024 shorts
// ---------------------------------------------------------------------------
__device__ __forceinline__ void wave_gemm256(
    const unsigned short* __restrict__ Ah, const unsigned short* __restrict__ Al,
    const unsigned short* __restrict__ Bh, const unsigned short* __restrict__ Bl,
    int rowA, int rowB, unsigned short* L, f4v acc[2][2]) {
    const int lane = threadIdx.x & 63;
    const int q = lane >> 4, r = lane & 15;
    const int lr = lane & 31, lc = lane >> 5;
    unsigned short* LAh = L;
    unsigned short* LAl = L + 1024;
    unsigned short* LBh = L + 2048;
    unsigned short* LBl = L + 3072;
    const unsigned short* pAh = Ah + (size_t)(rowA + lr) * C;
    const unsigned short* pAl = Al + (size_t)(rowA + lr) * C;
    const unsigned short* pBh = Bh + (size_t)(rowB + lr) * C;
    const unsigned short* pBl = Bl + (size_t)(rowB + lr) * C;

    for (int k0 = 0; k0 < C; k0 += 32) {
        // ensure prior chunk's ds_reads and stages are fully drained before
        // overwriting this wave's LDS slice
        __builtin_amdgcn_s_waitcnt(0);
        __builtin_amdgcn_wave_barrier();
#pragma unroll
        for (int c = 0; c < 2; ++c) {
            int ko = k0 + (2 * c + lc) * 8;
            stage16(pAh + ko, LAh + c * 512);
            stage16(pAl + ko, LAl + c * 512);
            stage16(pBh + ko, LBh + c * 512);
            stage16(pBl + ko, LBl + c * 512);
        }
        __builtin_amdgcn_s_waitcnt(0);
        __builtin_amdgcn_wave_barrier();
        b8v ah0 = *(const b8v*)&LAh[q * 256 + r * 8];
        b8v ah1 = *(const b8v*)&LAh[q * 256 + (16 + r) * 8];
        b8v al0 = *(const b8v*)&LAl[q * 256 + r * 8];
        b8v al1 = *(const b8v*)&LAl[q * 256 + (16 + r) * 8];
        b8v bh0 = *(const b8v*)&LBh[q * 256 + r * 8];
        b8v bh1 = *(const b8v*)&LBh[q * 256 + (16 + r) * 8];
        b8v bl0 = *(const b8v*)&LBl[q * 256 + r * 8];
        b8v bl1 = *(const b8v*)&LBl[q * 256 + (16 + r) * 8];

        acc[0][0] = __builtin_amdgcn_mfma_f32_16x16x32_bf16(ah0, bh0, acc[0][0], 0, 0, 0);
        acc[0][0] = __builtin_amdgcn_mfma_f32_16x16x32_bf16(ah0, bl0, acc[0][0], 0, 0, 0);
        acc[0][0] = __builtin_amdgcn_mfma_f32_16x16x32_bf16(al0, bh0, acc[0][0], 0, 0, 0);
        acc[0][1] = __builtin_amdgcn_mfma_f32_16x16x32_bf16(ah0, bh1, acc[0][1], 0, 0, 0);
        acc[0][1] = __builtin_amdgcn_mfma_f32_16x16x32_bf16(ah0, bl1, acc[0][1], 0, 0, 0);
        acc[0][1] = __builtin_amdgcn_mfma_f32_16x16x32_bf16(al0, bh1, acc[0][1], 0, 0, 0);
        acc[1][0] = __builtin_amdgcn_mfma_f32_16x16x32_bf16(ah1, bh0, acc[1][0], 0, 0, 0);
        acc[1][0] = __builtin_amdgcn_mfma_f32_16x16x32_bf16(ah1, bl0, acc[1][0], 0, 0, 0);
        acc[1][0] = __builtin_amdgcn_mfma_f32_16x16x32_bf16(al1, bh0, acc[1][0], 0, 0, 0);
        acc[1][1] = __builtin_amdgcn_mfma_f32_16x16x32_bf16(ah1, bh1, acc[1][1], 0, 0, 0);
        acc[1][1] = __builtin_amdgcn_mfma_f32_16x16x32_bf16(ah1, bl1, acc[1][1], 0, 0, 0);
        acc[1][1] = __builtin_amdgcn_mfma_f32_16x16x32_bf16(al1, bh1, acc[1][1], 0, 0, 0);
    }
}

// MODE 0: D = acc ; MODE 1: D = 1.5I - 0.5 acc ; MODE 2: triuvec(acc*sqrt(tr))
template <int MODE>
__global__ __launch_bounds__(256) void k_ns(
    const unsigned short* __restrict__ Ah, const unsigned short* __restrict__ Al,
    const unsigned short* __restrict__ Bh, const unsigned short* __restrict__ Bl,
    unsigned short* __restrict__ Dh, unsigned short* __restrict__ Dl,
    float* __restrict__ outF, const float* __restrict__ strbuf) {
    const int b = blockIdx.y;
    const int wave = threadIdx.x >> 6;
    int tm, tn;
    if (MODE == 2) {
        int p = blockIdx.x * 4 + wave, rem = 8; tm = 0;
        while (p >= rem) { p -= rem; ++tm; --rem; }
        tn = tm + p;
    } else {
        int tile = blockIdx.x * 4 + wave;
        tm = tile >> 3; tn = tile & 7;
    }
    __shared__ __align__(16) unsigned short lds[4][4096];
    const size_t mo = (size_t)b * C * C;
    f4v acc[2][2] = {};
    wave_gemm256(Ah + mo, Al + mo, Bh + mo, Bl + mo, tm * 32, tn * 32,
                 &lds[wave][0], acc);

    const int lane = threadIdx.x & 63, q = lane >> 4, r = lane & 15;
    if (MODE == 2) {
        float sc = strbuf[b];
#pragma unroll
        for (int rt = 0; rt < 2; ++rt)
#pragma unroll
            for (int ct = 0; ct < 2; ++ct) {
                int j = tn * 32 + ct * 16 + r;
#pragma unroll
                for (int reg = 0; reg < 4; ++reg) {
                    int i = tm * 32 + rt * 16 + q * 4 + reg;
                    if (j >= i)
                        outF[(size_t)b * OUTROW + (size_t)(i * C - (i * (i - 1)) / 2) +
                             (j - i)] = acc[rt][ct][reg] * sc;
                }
            }
    } else {
#pragma unroll
        for (int rt = 0; rt < 2; ++rt)
#pragma unroll
            for (int ct = 0; ct < 2; ++ct) {
                int j = tn * 32 + ct * 16 + r;
#pragma unroll
                for (int reg = 0; reg < 4; ++reg) {
                    int i = tm * 32 + rt * 16 + q * 4 + reg;
                    float v = acc[rt][ct][reg];
                    if (MODE == 1) v = ((i == j) ? 1.5f : 0.f) - 0.5f * v;
                    unsigned short h, l;
                    split2(v, h, l);
                    Dh[mo + (size_t)i * C + j] = h;
                    Dl[mo + (size_t)i * C + j] = l;
                }
            }
    }
}

// fused Ynew = Y@T (z=0), Znew = T@Z (z=1)
__global__ __launch_bounds__(256) void k_yz(
    const unsigned short* __restrict__ Yh, const unsigned short* __restrict__ Yl,
    const unsigned short* __restrict__ Th, const unsigned short* __restrict__ Tl,
    const unsigned short* __restrict__ Zh, const unsigned short* __restrict__ Zl,
    unsigned short* __restrict__ Ynh, unsigned short* __restrict__ Ynl,
    unsigned short* __restrict__ Znh, unsigned short* __restrict__ Znl) {
    const int b = blockIdx.y, zz = blockIdx.z;
    const int wave = threadIdx.x >> 6;
    int tile = blockIdx.x * 4 + wave;
    const int tm = tile >> 3, tn = tile & 7;
    const unsigned short* Ah = zz ? Th : Yh;
    const unsigned short* Al = zz ? Tl : Yl;
    const unsigned short* Bh = zz ? Zh : Th;
    const unsigned short* Bl = zz ? Zl : Tl;
    unsigned short* Dh = zz ? Znh : Ynh;
    unsigned short* Dl = zz ? Znl : Ynl;

    __shared__ __align__(16) unsigned short lds[4][4096];
    const size_t mo = (size_t)b * C * C;
    f4v acc[2][2] = {};
    wave_gemm256(Ah + mo, Al + mo, Bh + mo, Bl + mo, tm * 32, tn * 32,
                 &lds[wave][0], acc);

    const int lane = threadIdx.x & 63, q = lane >> 4, r = lane & 15;
#pragma unroll
    for (int rt = 0; rt < 2; ++rt)
#pragma unroll
        for (int ct = 0; ct < 2; ++ct) {
            int j = tn * 32 + ct * 16 + r;
#pragma unroll
            for (int reg = 0; reg < 4; ++reg) {
                int i = tm * 32 + rt * 16 + q * 4 + reg;
                unsigned short h, l;
                split2(acc[rt][ct][reg], h, l);
                Dh[mo + (size_t)i * C + j] = h;
                Dl[mo + (size_t)i * C + j] = l;
            }
        }
}

// ---------------------------------------------------------------------------
extern "C" void kernel_launch(void* const* d_in, const int* in_sizes, int n_in,
                              void* d_out, int out_size, void* d_ws, size_t ws_size,
                              hipStream_t stream) {
    const float* x = (const float*)d_in[0];
    float* out = (float*)d_out;

    unsigned short* W = (unsigned short*)d_ws;
    const size_t XN = (size_t)BATCH * C * HW;
    const size_t M = (size_t)BATCH * C * C;
    unsigned short* XH = W;
    unsigned short* XL = XH + XN;
    float* sbuf = (float*)(XL + XN);
    float* qbuf = sbuf + BATCH * C;
    float* trbuf = qbuf + BATCH * C;
    float* strbuf = trbuf + BATCH;
    unsigned short* P = (unsigned short*)(strbuf + BATCH);
    unsigned short* PA_h = P + 0 * M; unsigned short* PA_l = P + 1 * M;
    unsigned short* PB_h = P + 2 * M; unsigned short* PB_l = P + 3 * M;
    unsigned short* PC_h = P + 4 * M; unsigned short* PC_l = P + 5 * M;
    unsigned short* PD_h = P + 6 * M; unsigned short* PD_l = P + 7 * M;
    unsigned short* PE_h = P + 8 * M; unsigned short* PE_l = P + 9 * M;
    // fp32 partials alias PC..PE + beyond (dead until Y0 is written)
    float* part = (float*)PC_h;   // 10*32*7*4096 floats

    k_prep<<<dim3(BATCH * C), 256, 0, stream>>>(x, XH, XL, sbuf, qbuf);
    k_tr<<<dim3(BATCH), 256, 0, stream>>>(sbuf, qbuf, trbuf, strbuf);
    k_gram_split<<<dim3(10, BATCH, KSPLIT), 256, 0, stream>>>(XH, XL, part);
    k_reduce<<<dim3(10, BATCH), 256, 0, stream>>>(part, sbuf, trbuf,
                                                  PA_h, PA_l, PB_h, PB_l);

    dim3 gf(16, BATCH);          // full 64 tiles (4 waves/block)
    dim3 gu(9, BATCH);           // upper 36 tiles
    // Y0 = a @ z0 -> PC   (clobbers head of dead partials)
    k_ns<0><<<gf, 256, 0, stream>>>(PA_h, PA_l, PB_h, PB_l, PC_h, PC_l, nullptr, nullptr);
    // it0: T = 1.5I - 0.5 Z0@Y0 -> PD ; Y1 = Y0@T -> PA ; Z1 = T@Z0 -> PE
    k_ns<1><<<gf, 256, 0, stream>>>(PB_h, PB_l, PC_h, PC_l, PD_h, PD_l, nullptr, nullptr);
    k_yz<<<dim3(16, BATCH, 2), 256, 0, stream>>>(PC_h, PC_l, PD_h, PD_l, PB_h, PB_l,
                                                 PA_h, PA_l, PE_h, PE_l);
    // it1: T = 1.5I - 0.5 Z1@Y1 -> PB ; Y2 = Y1@T -> PC ; Z2 = T@Z1 -> PD
    k_ns<1><<<gf, 256, 0, stream>>>(PE_h, PE_l, PA_h, PA_l, PB_h, PB_l, nullptr, nullptr);
    k_yz<<<dim3(16, BATCH, 2), 256, 0, stream>>>(PA_h, PA_l, PB_h, PB_l, PE_h, PE_l,
                                                 PC_h, PC_l, PD_h, PD_l);
    // it2: T = 1.5I - 0.5 Z2@Y2 -> PA ; Y3 = Y2@T -> PB ; Z3 = T@Z2 -> PE
    k_ns<1><<<gf, 256, 0, stream>>>(PD_h, PD_l, PC_h, PC_l, PA_h, PA_l, nullptr, nullptr);
    k_yz<<<dim3(16, BATCH, 2), 256, 0, stream>>>(PC_h, PC_l, PA_h, PA_l, PD_h, PD_l,
                                                 PB_h, PB_l, PE_h, PE_l);
    // it3: T = 1.5I - 0.5 Z3@Y3 -> PC ; out = triuvec((Y3@T) * sqrt(tr))
    k_ns<1><<<gf, 256, 0, stream>>>(PE_h, PE_l, PB_h, PB_l, PC_h, PC_l, nullptr, nullptr);
    k_ns<2><<<gu, 256, 0, stream>>>(PB_h, PB_l, PC_h, PC_l, nullptr, nullptr, out, strbuf);
}

// Round 4
// 470.206 us; speedup vs baseline: 1.3516x; 1.0991x over previous
//
#include <hip/hip_runtime.h>
#include <hip/hip_bf16.h>
#include <math.h>

#define BATCH 32
#define C 256
#define HW 3136
#define OUTROW 32896
#define KSPLIT 7
#define KCHUNK 448   // HW / KSPLIT, multiple of 64

typedef __bf16 b8v __attribute__((ext_vector_type(8)));
typedef float  f4v __attribute__((ext_vector_type(4)));

__device__ __forceinline__ unsigned short f2bf(float f) {
    union { float f; unsigned u; } v; v.f = f;
    unsigned r = v.u + 0x7FFFu + ((v.u >> 16) & 1u);
    return (unsigned short)(r >> 16);
}
__device__ __forceinline__ float bf2f(unsigned short h) {
    union { unsigned u; float f; } v; v.u = ((unsigned)h) << 16; return v.f;
}
__device__ __forceinline__ void split2(float x, unsigned short& h, unsigned short& l) {
    h = f2bf(x);
    l = f2bf(x - bf2f(h));
}

__device__ __forceinline__ void stage16(const unsigned short* g, unsigned short* l) {
    __builtin_amdgcn_global_load_lds(
        (const __attribute__((address_space(1))) unsigned int*)g,
        (__attribute__((address_space(3))) unsigned int*)l,
        16, 0, 0);
}

__device__ __forceinline__ float wave_sum(float v) {
    for (int o = 32; o; o >>= 1) v += __shfl_down(v, o, 64);
    return v;
}

// ---------------------------------------------------------------------------
// prep: x -> hi/lo bf16 split, per-row sum and sum-of-squares
// ---------------------------------------------------------------------------
__global__ void k_prep(const float* __restrict__ x, unsigned short* __restrict__ xh,
                       unsigned short* __restrict__ xl, float* __restrict__ sbuf,
                       float* __restrict__ qbuf) {
    const int row = blockIdx.x;
    const float4* xr = (const float4*)(x + (size_t)row * HW);
    ushort4* hr = (ushort4*)(xh + (size_t)row * HW);
    ushort4* lr = (ushort4*)(xl + (size_t)row * HW);
    float s = 0.f, q = 0.f;
    for (int c = threadIdx.x; c < HW / 4; c += 256) {
        float4 v = xr[c];
        ushort4 h, l;
        split2(v.x, h.x, l.x); split2(v.y, h.y, l.y);
        split2(v.z, h.z, l.z); split2(v.w, h.w, l.w);
        hr[c] = h; lr[c] = l;
        s += v.x + v.y + v.z + v.w;
        q += v.x * v.x + v.y * v.y + v.z * v.z + v.w * v.w;
    }
    s = wave_sum(s); q = wave_sum(q);
    __shared__ float ss[4], qq[4];
    if ((threadIdx.x & 63) == 0) { ss[threadIdx.x >> 6] = s; qq[threadIdx.x >> 6] = q; }
    __syncthreads();
    if (threadIdx.x == 0) {
        sbuf[row] = ss[0] + ss[1] + ss[2] + ss[3];
        qbuf[row] = qq[0] + qq[1] + qq[2] + qq[3];
    }
}

__global__ void k_tr(const float* __restrict__ sbuf, const float* __restrict__ qbuf,
                     float* __restrict__ trbuf, float* __restrict__ strbuf) {
    const int b = blockIdx.x, t = threadIdx.x;
    const float invn = 1.f / (float)HW, invn2 = invn * invn;
    float sv = sbuf[b * C + t];
    float v = qbuf[b * C + t] * invn - sv * sv * invn2;
    v = wave_sum(v);
    __shared__ float red[4];
    if ((t & 63) == 0) red[t >> 6] = v;
    __syncthreads();
    if (t == 0) {
        float tr = red[0] + red[1] + red[2] + red[3];
        trbuf[b] = tr;
        strbuf[b] = sqrtf(tr);
    }
}

// ---------------------------------------------------------------------------
// gram split-K: grid (10 pairs, 32 batch, 7 splits); 64x64 tile, 4 waves,
// K-step 64 per barrier pair (halved barrier count), fp32 partials out.
// ---------------------------------------------------------------------------
__global__ __launch_bounds__(256) void k_gram_split(
    const unsigned short* __restrict__ Xh, const unsigned short* __restrict__ Xl,
    float* __restrict__ part) {
    const int b = blockIdx.y, z = blockIdx.z;
    int p = blockIdx.x, tm = 0, rem = 4;
    while (p >= rem) { p -= rem; ++tm; --rem; }
    const int tn = tm + p;

    const int tid = threadIdx.x, wave = tid >> 6, lane = tid & 63;
    const int wr = wave >> 1, wc = wave & 1;

    __shared__ __align__(16) unsigned short lds[4][4096];  // [c(8)][row(64)][8]

    const size_t matAB = (size_t)b * C * (size_t)HW;
    const unsigned short* src;
    {
        const unsigned short* s0 = (wave == 0) ? Xh : (wave == 1) ? Xl : (wave == 2) ? Xh : Xl;
        const int r0 = (wave < 2) ? tm * 64 : tn * 64;
        src = s0 + matAB + (size_t)(r0 + lane) * HW + z * KCHUNK;
    }
    unsigned short* lbuf = &lds[wave][0];

    f4v acc[2][2] = {};
    const int q = lane >> 4, r = lane & 15;
    const int mA0 = q * 512 + (wr * 32 + r) * 8;
    const int nB0 = q * 512 + (wc * 32 + r) * 8;

    for (int k0 = 0; k0 < KCHUNK; k0 += 64) {
        __syncthreads();
#pragma unroll
        for (int c = 0; c < 8; ++c) stage16(src + k0 + c * 8, lbuf + c * 512);
        __syncthreads();
#pragma unroll
        for (int s = 0; s < 2; ++s) {
            const int o = s * 2048;
            b8v ah0 = *(const b8v*)&lds[0][o + mA0];
            b8v ah1 = *(const b8v*)&lds[0][o + mA0 + 128];
            b8v al0 = *(const b8v*)&lds[1][o + mA0];
            b8v al1 = *(const b8v*)&lds[1][o + mA0 + 128];
            b8v bh0 = *(const b8v*)&lds[2][o + nB0];
            b8v bh1 = *(const b8v*)&lds[2][o + nB0 + 128];
            b8v bl0 = *(const b8v*)&lds[3][o + nB0];
            b8v bl1 = *(const b8v*)&lds[3][o + nB0 + 128];

            acc[0][0] = __builtin_amdgcn_mfma_f32_16x16x32_bf16(ah0, bh0, acc[0][0], 0, 0, 0);
            acc[0][0] = __builtin_amdgcn_mfma_f32_16x16x32_bf16(ah0, bl0, acc[0][0], 0, 0, 0);
            acc[0][0] = __builtin_amdgcn_mfma_f32_16x16x32_bf16(al0, bh0, acc[0][0], 0, 0, 0);
            acc[0][1] = __builtin_amdgcn_mfma_f32_16x16x32_bf16(ah0, bh1, acc[0][1], 0, 0, 0);
            acc[0][1] = __builtin_amdgcn_mfma_f32_16x16x32_bf16(ah0, bl1, acc[0][1], 0, 0, 0);
            acc[0][1] = __builtin_amdgcn_mfma_f32_16x16x32_bf16(al0, bh1, acc[0][1], 0, 0, 0);
            acc[1][0] = __builtin_amdgcn_mfma_f32_16x16x32_bf16(ah1, bh0, acc[1][0], 0, 0, 0);
            acc[1][0] = __builtin_amdgcn_mfma_f32_16x16x32_bf16(ah1, bl0, acc[1][0], 0, 0, 0);
            acc[1][0] = __builtin_amdgcn_mfma_f32_16x16x32_bf16(al1, bh0, acc[1][0], 0, 0, 0);
            acc[1][1] = __builtin_amdgcn_mfma_f32_16x16x32_bf16(ah1, bh1, acc[1][1], 0, 0, 0);
            acc[1][1] = __builtin_amdgcn_mfma_f32_16x16x32_bf16(ah1, bl1, acc[1][1], 0, 0, 0);
            acc[1][1] = __builtin_amdgcn_mfma_f32_16x16x32_bf16(al1, bh1, acc[1][1], 0, 0, 0);
        }
    }

    float* pt = part + (((size_t)blockIdx.x * BATCH + b) * KSPLIT + z) * 4096;
#pragma unroll
    for (int rt = 0; rt < 2; ++rt)
#pragma unroll
        for (int ct = 0; ct < 2; ++ct)
#pragma unroll
            for (int reg = 0; reg < 4; ++reg) {
                int row = wr * 32 + rt * 16 + q * 4 + reg;
                int col = wc * 32 + ct * 16 + r;
                pt[row * 64 + col] = acc[rt][ct][reg];
            }
}

// ---------------------------------------------------------------------------
// reduce partials -> a (Ahh/All) and z0 (Zhh/Zll), mirrored via LDS transpose
// ---------------------------------------------------------------------------
__global__ __launch_bounds__(256) void k_reduce(
    const float* __restrict__ part, const float* __restrict__ sbuf,
    const float* __restrict__ trbuf,
    unsigned short* __restrict__ Ahh, unsigned short* __restrict__ All,
    unsigned short* __restrict__ Zhh, unsigned short* __restrict__ Zll) {
    const int b = blockIdx.y;
    int p = blockIdx.x, tm = 0, rem = 4;
    while (p >= rem) { p -= rem; ++tm; --rem; }
    const int tn = tm + p;

    const float* pb = part + ((size_t)blockIdx.x * BATCH + b) * KSPLIT * 4096;
    const int t = threadIdx.x;
    const int row = t >> 2, c0 = (t & 3) * 16;

    float s[16];
#pragma unroll
    for (int u = 0; u < 16; ++u) s[u] = 0.f;
    for (int sp = 0; sp < KSPLIT; ++sp) {
        const float* q4 = pb + sp * 4096 + row * 64 + c0;
#pragma unroll
        for (int u4 = 0; u4 < 4; ++u4) {
            float4 v = *(const float4*)(q4 + u4 * 4);
            s[u4 * 4 + 0] += v.x; s[u4 * 4 + 1] += v.y;
            s[u4 * 4 + 2] += v.z; s[u4 * 4 + 3] += v.w;
        }
    }

    const float invn = 1.f / (float)HW, invn2 = invn * invn;
    const float tr = trbuf[b];
    const int gi = tm * 64 + row;
    const float si = sbuf[b * C + gi];
    const size_t mo = (size_t)b * C * C;

    __shared__ unsigned short tAh[64][66], tAl[64][66], tZh[64][66], tZl[64][66];
    unsigned short vAh[16], vAl[16], vZh[16], vZl[16];
#pragma unroll
    for (int u = 0; u < 16; ++u) {
        int gj = tn * 64 + c0 + u;
        float sj = sbuf[b * C + gj];
        float a = (s[u] * invn - si * sj * invn2) / tr;
        split2(a, vAh[u], vAl[u]);
        float zv = ((gi == gj) ? 1.5f : 0.f) - 0.5f * a;
        split2(zv, vZh[u], vZl[u]);
        tAh[row][c0 + u] = vAh[u]; tAl[row][c0 + u] = vAl[u];
        tZh[row][c0 + u] = vZh[u]; tZl[row][c0 + u] = vZl[u];
    }
    size_t off = mo + (size_t)gi * C + tn * 64 + c0;
#pragma unroll
    for (int u4 = 0; u4 < 4; ++u4) {
        *(ushort4*)&Ahh[off + u4 * 4] = *(ushort4*)&vAh[u4 * 4];
        *(ushort4*)&All[off + u4 * 4] = *(ushort4*)&vAl[u4 * 4];
        *(ushort4*)&Zhh[off + u4 * 4] = *(ushort4*)&vZh[u4 * 4];
        *(ushort4*)&Zll[off + u4 * 4] = *(ushort4*)&vZl[u4 * 4];
    }
    if (tm != tn) {
        __syncthreads();
        const int mr = t >> 2, mc0 = (t & 3) * 16;
        size_t moff = mo + (size_t)(tn * 64 + mr) * C + tm * 64 + mc0;
        unsigned short wAh[16], wAl[16], wZh[16], wZl[16];
#pragma unroll
        for (int u = 0; u < 16; ++u) {
            wAh[u] = tAh[mc0 + u][mr]; wAl[u] = tAl[mc0 + u][mr];
            wZh[u] = tZh[mc0 + u][mr]; wZl[u] = tZl[mc0 + u][mr];
        }
#pragma unroll
        for (int u4 = 0; u4 < 4; ++u4) {
            *(ushort4*)&Ahh[moff + u4 * 4] = *(ushort4*)&wAh[u4 * 4];
            *(ushort4*)&All[moff + u4 * 4] = *(ushort4*)&wAl[u4 * 4];
            *(ushort4*)&Zhh[moff + u4 * 4] = *(ushort4*)&wZh[u4 * 4];
            *(ushort4*)&Zll[moff + u4 * 4] = *(ushort4*)&wZl[u4 * 4];
        }
    }
}

// ---------------------------------------------------------------------------
// NS GEMM core: per-wave 32x32 tile, K=256, fragments loaded DIRECTLY from
// global (row-major => each fragment is a contiguous 16B lane load), register
// double-buffered. No LDS, no barriers, no full drains.
// ---------------------------------------------------------------------------
__device__ __forceinline__ void wave_gemm_direct(
    const unsigned short* __restrict__ Ah, const unsigned short* __restrict__ Al,
    const unsigned short* __restrict__ Bh, const unsigned short* __restrict__ Bl,
    int rowA, int rowB, f4v acc[2][2]) {
    const int lane = threadIdx.x & 63;
    const int q = lane >> 4, r = lane & 15;
    const size_t oA0 = (size_t)(rowA + r) * C + q * 8;
    const size_t oA1 = oA0 + 16 * C;
    const size_t oB0 = (size_t)(rowB + r) * C + q * 8;
    const size_t oB1 = oB0 + 16 * C;

    b8v f[2][8];
#define LOADF(buf, k0)                                    \
    do {                                                  \
        f[buf][0] = *(const b8v*)(Ah + oA0 + (k0));       \
        f[buf][1] = *(const b8v*)(Ah + oA1 + (k0));       \
        f[buf][2] = *(const b8v*)(Al + oA0 + (k0));       \
        f[buf][3] = *(const b8v*)(Al + oA1 + (k0));       \
        f[buf][4] = *(const b8v*)(Bh + oB0 + (k0));       \
        f[buf][5] = *(const b8v*)(Bh + oB1 + (k0));       \
        f[buf][6] = *(const b8v*)(Bl + oB0 + (k0));       \
        f[buf][7] = *(const b8v*)(Bl + oB1 + (k0));       \
    } while (0)

    LOADF(0, 0);
#pragma unroll
    for (int kc = 0; kc < 8; ++kc) {
        const int cb = kc & 1, nb = cb ^ 1;
        if (kc < 7) LOADF(nb, (kc + 1) * 32);
        b8v ah0 = f[cb][0], ah1 = f[cb][1], al0 = f[cb][2], al1 = f[cb][3];
        b8v bh0 = f[cb][4], bh1 = f[cb][5], bl0 = f[cb][6], bl1 = f[cb][7];
        acc[0][0] = __builtin_amdgcn_mfma_f32_16x16x32_bf16(ah0, bh0, acc[0][0], 0, 0, 0);
        acc[0][0] = __builtin_amdgcn_mfma_f32_16x16x32_bf16(ah0, bl0, acc[0][0], 0, 0, 0);
        acc[0][0] = __builtin_amdgcn_mfma_f32_16x16x32_bf16(al0, bh0, acc[0][0], 0, 0, 0);
        acc[0][1] = __builtin_amdgcn_mfma_f32_16x16x32_bf16(ah0, bh1, acc[0][1], 0, 0, 0);
        acc[0][1] = __builtin_amdgcn_mfma_f32_16x16x32_bf16(ah0, bl1, acc[0][1], 0, 0, 0);
        acc[0][1] = __builtin_amdgcn_mfma_f32_16x16x32_bf16(al0, bh1, acc[0][1], 0, 0, 0);
        acc[1][0] = __builtin_amdgcn_mfma_f32_16x16x32_bf16(ah1, bh0, acc[1][0], 0, 0, 0);
        acc[1][0] = __builtin_amdgcn_mfma_f32_16x16x32_bf16(ah1, bl0, acc[1][0], 0, 0, 0);
        acc[1][0] = __builtin_amdgcn_mfma_f32_16x16x32_bf16(al1, bh0, acc[1][0], 0, 0, 0);
        acc[1][1] = __builtin_amdgcn_mfma_f32_16x16x32_bf16(ah1, bh1, acc[1][1], 0, 0, 0);
        acc[1][1] = __builtin_amdgcn_mfma_f32_16x16x32_bf16(ah1, bl1, acc[1][1], 0, 0, 0);
        acc[1][1] = __builtin_amdgcn_mfma_f32_16x16x32_bf16(al1, bh1, acc[1][1], 0, 0, 0);
    }
#undef LOADF
}

// MODE 0: D = acc ; MODE 1: D = 1.5I - 0.5 acc ; MODE 2: triuvec(acc*sqrt(tr))
template <int MODE>
__global__ __launch_bounds__(256) void k_ns2(
    const unsigned short* __restrict__ Ah, const unsigned short* __restrict__ Al,
    const unsigned short* __restrict__ Bh, const unsigned short* __restrict__ Bl,
    unsigned short* __restrict__ Dh, unsigned short* __restrict__ Dl,
    float* __restrict__ outF, const float* __restrict__ strbuf) {
    const int b = blockIdx.y;
    const int wave = threadIdx.x >> 6;
    int tm, tn;
    if (MODE == 2) {
        int p = blockIdx.x * 4 + wave, rem = 8; tm = 0;
        while (p >= rem) { p -= rem; ++tm; --rem; }
        tn = tm + p;
    } else {
        int tile = blockIdx.x * 4 + wave;
        tm = tile >> 3; tn = tile & 7;
    }
    const size_t mo = (size_t)b * C * C;
    f4v acc[2][2] = {};
    wave_gemm_direct(Ah + mo, Al + mo, Bh + mo, Bl + mo, tm * 32, tn * 32, acc);

    const int lane = threadIdx.x & 63, q = lane >> 4, r = lane & 15;
    if (MODE == 2) {
        float sc = strbuf[b];
#pragma unroll
        for (int rt = 0; rt < 2; ++rt)
#pragma unroll
            for (int ct = 0; ct < 2; ++ct) {
                int j = tn * 32 + ct * 16 + r;
#pragma unroll
                for (int reg = 0; reg < 4; ++reg) {
                    int i = tm * 32 + rt * 16 + q * 4 + reg;
                    if (j >= i)
                        outF[(size_t)b * OUTROW + (size_t)(i * C - (i * (i - 1)) / 2) +
                             (j - i)] = acc[rt][ct][reg] * sc;
                }
            }
    } else {
#pragma unroll
        for (int rt = 0; rt < 2; ++rt)
#pragma unroll
            for (int ct = 0; ct < 2; ++ct) {
                int j = tn * 32 + ct * 16 + r;
#pragma unroll
                for (int reg = 0; reg < 4; ++reg) {
                    int i = tm * 32 + rt * 16 + q * 4 + reg;
                    float v = acc[rt][ct][reg];
                    if (MODE == 1) v = ((i == j) ? 1.5f : 0.f) - 0.5f * v;
                    unsigned short h, l;
                    split2(v, h, l);
                    Dh[mo + (size_t)i * C + j] = h;
                    Dl[mo + (size_t)i * C + j] = l;
                }
            }
    }
}

// fused Ynew = Y@T (z=0), Znew = T@Z (z=1)
__global__ __launch_bounds__(256) void k_yz2(
    const unsigned short* __restrict__ Yh, const unsigned short* __restrict__ Yl,
    const unsigned short* __restrict__ Th, const unsigned short* __restrict__ Tl,
    const unsigned short* __restrict__ Zh, const unsigned short* __restrict__ Zl,
    unsigned short* __restrict__ Ynh, unsigned short* __restrict__ Ynl,
    unsigned short* __restrict__ Znh, unsigned short* __restrict__ Znl) {
    const int b = blockIdx.y, zz = blockIdx.z;
    const int wave = threadIdx.x >> 6;
    int tile = blockIdx.x * 4 + wave;
    const int tm = tile >> 3, tn = tile & 7;
    const unsigned short* Ah = zz ? Th : Yh;
    const unsigned short* Al = zz ? Tl : Yl;
    const unsigned short* Bh = zz ? Zh : Th;
    const unsigned short* Bl = zz ? Zl : Tl;
    unsigned short* Dh = zz ? Znh : Ynh;
    unsigned short* Dl = zz ? Znl : Ynl;

    const size_t mo = (size_t)b * C * C;
    f4v acc[2][2] = {};
    wave_gemm_direct(Ah + mo, Al + mo, Bh + mo, Bl + mo, tm * 32, tn * 32, acc);

    const int lane = threadIdx.x & 63, q = lane >> 4, r = lane & 15;
#pragma unroll
    for (int rt = 0; rt < 2; ++rt)
#pragma unroll
        for (int ct = 0; ct < 2; ++ct) {
            int j = tn * 32 + ct * 16 + r;
#pragma unroll
            for (int reg = 0; reg < 4; ++reg) {
                int i = tm * 32 + rt * 16 + q * 4 + reg;
                unsigned short h, l;
                split2(acc[rt][ct][reg], h, l);
                Dh[mo + (size_t)i * C + j] = h;
                Dl[mo + (size_t)i * C + j] = l;
            }
        }
}

// ---------------------------------------------------------------------------
extern "C" void kernel_launch(void* const* d_in, const int* in_sizes, int n_in,
                              void* d_out, int out_size, void* d_ws, size_t ws_size,
                              hipStream_t stream) {
    const float* x = (const float*)d_in[0];
    float* out = (float*)d_out;

    unsigned short* W = (unsigned short*)d_ws;
    const size_t XN = (size_t)BATCH * C * HW;
    const size_t M = (size_t)BATCH * C * C;
    unsigned short* XH = W;
    unsigned short* XL = XH + XN;
    float* sbuf = (float*)(XL + XN);
    float* qbuf = sbuf + BATCH * C;
    float* trbuf = qbuf + BATCH * C;
    float* strbuf = trbuf + BATCH;
    unsigned short* P = (unsigned short*)(strbuf + BATCH);
    unsigned short* PA_h = P + 0 * M; unsigned short* PA_l = P + 1 * M;
    unsigned short* PB_h = P + 2 * M; unsigned short* PB_l = P + 3 * M;
    unsigned short* PC_h = P + 4 * M; unsigned short* PC_l = P + 5 * M;
    unsigned short* PD_h = P + 6 * M; unsigned short* PD_l = P + 7 * M;
    unsigned short* PE_h = P + 8 * M; unsigned short* PE_l = P + 9 * M;
    // fp32 partials alias PC..PE + beyond (dead until Y0 is written)
    float* part = (float*)PC_h;   // 10*32*7*4096 floats

    k_prep<<<dim3(BATCH * C), 256, 0, stream>>>(x, XH, XL, sbuf, qbuf);
    k_tr<<<dim3(BATCH), 256, 0, stream>>>(sbuf, qbuf, trbuf, strbuf);
    k_gram_split<<<dim3(10, BATCH, KSPLIT), 256, 0, stream>>>(XH, XL, part);
    k_reduce<<<dim3(10, BATCH), 256, 0, stream>>>(part, sbuf, trbuf,
                                                  PA_h, PA_l, PB_h, PB_l);

    dim3 gf(16, BATCH);          // full 64 tiles (4 waves/block)
    dim3 gu(9, BATCH);           // upper 36 tiles
    // Y0 = a @ z0 -> PC
    k_ns2<0><<<gf, 256, 0, stream>>>(PA_h, PA_l, PB_h, PB_l, PC_h, PC_l, nullptr, nullptr);
    // it0: T = 1.5I - 0.5 Z0@Y0 -> PD ; Y1 = Y0@T -> PA ; Z1 = T@Z0 -> PE
    k_ns2<1><<<gf, 256, 0, stream>>>(PB_h, PB_l, PC_h, PC_l, PD_h, PD_l, nullptr, nullptr);
    k_yz2<<<dim3(16, BATCH, 2), 256, 0, stream>>>(PC_h, PC_l, PD_h, PD_l, PB_h, PB_l,
                                                  PA_h, PA_l, PE_h, PE_l);
    // it1: T = 1.5I - 0.5 Z1@Y1 -> PB ; Y2 = Y1@T -> PC ; Z2 = T@Z1 -> PD
    k_ns2<1><<<gf, 256, 0, stream>>>(PE_h, PE_l, PA_h, PA_l, PB_h, PB_l, nullptr, nullptr);
    k_yz2<<<dim3(16, BATCH, 2), 256, 0, stream>>>(PA_h, PA_l, PB_h, PB_l, PE_h, PE_l,
                                                  PC_h, PC_l, PD_h, PD_l);
    // it2: T = 1.5I - 0.5 Z2@Y2 -> PA ; Y3 = Y2@T -> PB ; Z3 = T@Z2 -> PE
    k_ns2<1><<<gf, 256, 0, stream>>>(PD_h, PD_l, PC_h, PC_l, PA_h, PA_l, nullptr, nullptr);
    k_yz2<<<dim3(16, BATCH, 2), 256, 0, stream>>>(PC_h, PC_l, PA_h, PA_l, PD_h, PD_l,
                                                  PB_h, PB_l, PE_h, PE_l);
    // it3: T = 1.5I - 0.5 Z3@Y3 -> PC ; out = triuvec((Y3@T) * sqrt(tr))
    k_ns2<1><<<gf, 256, 0, stream>>>(PE_h, PE_l, PB_h, PB_l, PC_h, PC_l, nullptr, nullptr);
    k_ns2<2><<<gu, 256, 0, stream>>>(PB_h, PB_l, PC_h, PC_l, nullptr, nullptr, out, strbuf);
}

// Round 5
// 437.078 us; speedup vs baseline: 1.4540x; 1.0758x over previous
//
#include <hip/hip_runtime.h>
#include <hip/hip_bf16.h>
#include <math.h>

#define BATCH 32
#define C 256
#define HW 3136
#define OUTROW 32896
#define KSPLIT 7
#define KCHUNK 448   // HW / KSPLIT, multiple of 64

typedef __bf16 b8v __attribute__((ext_vector_type(8)));
typedef float  f4v __attribute__((ext_vector_type(4)));

__device__ __forceinline__ unsigned short f2bf(float f) {
    union { float f; unsigned u; } v; v.f = f;
    unsigned r = v.u + 0x7FFFu + ((v.u >> 16) & 1u);
    return (unsigned short)(r >> 16);
}
__device__ __forceinline__ float bf2f(unsigned short h) {
    union { unsigned u; float f; } v; v.u = ((unsigned)h) << 16; return v.f;
}
__device__ __forceinline__ void split2(float x, unsigned short& h, unsigned short& l) {
    h = f2bf(x);
    l = f2bf(x - bf2f(h));
}

__device__ __forceinline__ void stage16(const unsigned short* g, unsigned short* l) {
    __builtin_amdgcn_global_load_lds(
        (const __attribute__((address_space(1))) unsigned int*)g,
        (__attribute__((address_space(3))) unsigned int*)l,
        16, 0, 0);
}

__device__ __forceinline__ float wave_sum(float v) {
    for (int o = 32; o; o >>= 1) v += __shfl_down(v, o, 64);
    return v;
}

// ---------------------------------------------------------------------------
// prep: x -> hi/lo bf16 split, per-row sum and sum-of-squares
// ---------------------------------------------------------------------------
__global__ void k_prep(const float* __restrict__ x, unsigned short* __restrict__ xh,
                       unsigned short* __restrict__ xl, float* __restrict__ sbuf,
                       float* __restrict__ qbuf) {
    const int row = blockIdx.x;
    const float4* xr = (const float4*)(x + (size_t)row * HW);
    ushort4* hr = (ushort4*)(xh + (size_t)row * HW);
    ushort4* lr = (ushort4*)(xl + (size_t)row * HW);
    float s = 0.f, q = 0.f;
    for (int c = threadIdx.x; c < HW / 4; c += 256) {
        float4 v = xr[c];
        ushort4 h, l;
        split2(v.x, h.x, l.x); split2(v.y, h.y, l.y);
        split2(v.z, h.z, l.z); split2(v.w, h.w, l.w);
        hr[c] = h; lr[c] = l;
        s += v.x + v.y + v.z + v.w;
        q += v.x * v.x + v.y * v.y + v.z * v.z + v.w * v.w;
    }
    s = wave_sum(s); q = wave_sum(q);
    __shared__ float ss[4], qq[4];
    if ((threadIdx.x & 63) == 0) { ss[threadIdx.x >> 6] = s; qq[threadIdx.x >> 6] = q; }
    __syncthreads();
    if (threadIdx.x == 0) {
        sbuf[row] = ss[0] + ss[1] + ss[2] + ss[3];
        qbuf[row] = qq[0] + qq[1] + qq[2] + qq[3];
    }
}

__global__ void k_tr(const float* __restrict__ sbuf, const float* __restrict__ qbuf,
                     float* __restrict__ trbuf, float* __restrict__ strbuf) {
    const int b = blockIdx.x, t = threadIdx.x;
    const float invn = 1.f / (float)HW, invn2 = invn * invn;
    float sv = sbuf[b * C + t];
    float v = qbuf[b * C + t] * invn - sv * sv * invn2;
    v = wave_sum(v);
    __shared__ float red[4];
    if ((t & 63) == 0) red[t >> 6] = v;
    __syncthreads();
    if (t == 0) {
        float tr = red[0] + red[1] + red[2] + red[3];
        trbuf[b] = tr;
        strbuf[b] = sqrtf(tr);
    }
}

// ---------------------------------------------------------------------------
// gram split-K, XCD-swizzled flat grid (2240 blocks), double-buffered LDS.
// Group g=(b,z) pinned to XCD g%8 so all 10 pair-blocks share L2 panels.
// ---------------------------------------------------------------------------
__global__ __launch_bounds__(256) void k_gram_split(
    const unsigned short* __restrict__ Xh, const unsigned short* __restrict__ Xl,
    float* __restrict__ part) {
    const int bid = blockIdx.x;
    const int x8 = bid & 7;
    const int t8 = bid >> 3;
    const int pairIdx = t8 % 10;
    const int ghi = t8 / 10;
    const int g = ghi * 8 + x8;       // 0..223
    const int b = g & 31;
    const int z = g >> 5;             // 0..6

    int p = pairIdx, tm = 0, rem = 4;
    while (p >= rem) { p -= rem; ++tm; --rem; }
    const int tn = tm + p;

    const int tid = threadIdx.x, wave = tid >> 6, lane = tid & 63;
    const int wr = wave >> 1, wc = wave & 1;

    __shared__ __align__(16) unsigned short lds[2][4][4096]; // [buf][op][c(8)][row(64)][8]

    const size_t matAB = (size_t)b * C * (size_t)HW;
    const unsigned short* src;
    {
        const unsigned short* s0 = (wave == 0) ? Xh : (wave == 1) ? Xl : (wave == 2) ? Xh : Xl;
        const int r0 = (wave < 2) ? tm * 64 : tn * 64;
        src = s0 + matAB + (size_t)(r0 + lane) * HW + z * KCHUNK;
    }

    f4v acc[2][2] = {};
    const int q = lane >> 4, r = lane & 15;
    const int mA0 = q * 512 + (wr * 32 + r) * 8;
    const int nB0 = q * 512 + (wc * 32 + r) * 8;

    // prologue stage into buf 0
#pragma unroll
    for (int c = 0; c < 8; ++c) stage16(src + c * 8, &lds[0][wave][c * 512]);

    for (int s = 0; s < KCHUNK / 64; ++s) {
        const int cb = s & 1, nb = cb ^ 1;
        __syncthreads();   // drains vmcnt -> buf cb ready; prior reads of nb done
        if (s < KCHUNK / 64 - 1) {
            const int k0 = (s + 1) * 64;
#pragma unroll
            for (int c = 0; c < 8; ++c) stage16(src + k0 + c * 8, &lds[nb][wave][c * 512]);
        }
#pragma unroll
        for (int h = 0; h < 2; ++h) {
            const int o = h * 2048;
            b8v ah0 = *(const b8v*)&lds[cb][0][o + mA0];
            b8v ah1 = *(const b8v*)&lds[cb][0][o + mA0 + 128];
            b8v al0 = *(const b8v*)&lds[cb][1][o + mA0];
            b8v al1 = *(const b8v*)&lds[cb][1][o + mA0 + 128];
            b8v bh0 = *(const b8v*)&lds[cb][2][o + nB0];
            b8v bh1 = *(const b8v*)&lds[cb][2][o + nB0 + 128];
            b8v bl0 = *(const b8v*)&lds[cb][3][o + nB0];
            b8v bl1 = *(const b8v*)&lds[cb][3][o + nB0 + 128];

            acc[0][0] = __builtin_amdgcn_mfma_f32_16x16x32_bf16(ah0, bh0, acc[0][0], 0, 0, 0);
            acc[0][0] = __builtin_amdgcn_mfma_f32_16x16x32_bf16(ah0, bl0, acc[0][0], 0, 0, 0);
            acc[0][0] = __builtin_amdgcn_mfma_f32_16x16x32_bf16(al0, bh0, acc[0][0], 0, 0, 0);
            acc[0][1] = __builtin_amdgcn_mfma_f32_16x16x32_bf16(ah0, bh1, acc[0][1], 0, 0, 0);
            acc[0][1] = __builtin_amdgcn_mfma_f32_16x16x32_bf16(ah0, bl1, acc[0][1], 0, 0, 0);
            acc[0][1] = __builtin_amdgcn_mfma_f32_16x16x32_bf16(al0, bh1, acc[0][1], 0, 0, 0);
            acc[1][0] = __builtin_amdgcn_mfma_f32_16x16x32_bf16(ah1, bh0, acc[1][0], 0, 0, 0);
            acc[1][0] = __builtin_amdgcn_mfma_f32_16x16x32_bf16(ah1, bl0, acc[1][0], 0, 0, 0);
            acc[1][0] = __builtin_amdgcn_mfma_f32_16x16x32_bf16(al1, bh0, acc[1][0], 0, 0, 0);
            acc[1][1] = __builtin_amdgcn_mfma_f32_16x16x32_bf16(ah1, bh1, acc[1][1], 0, 0, 0);
            acc[1][1] = __builtin_amdgcn_mfma_f32_16x16x32_bf16(ah1, bl1, acc[1][1], 0, 0, 0);
            acc[1][1] = __builtin_amdgcn_mfma_f32_16x16x32_bf16(al1, bh1, acc[1][1], 0, 0, 0);
        }
    }

    float* pt = part + (((size_t)pairIdx * BATCH + b) * KSPLIT + z) * 4096;
#pragma unroll
    for (int rt = 0; rt < 2; ++rt)
#pragma unroll
        for (int ct = 0; ct < 2; ++ct)
#pragma unroll
            for (int reg = 0; reg < 4; ++reg) {
                int row = wr * 32 + rt * 16 + q * 4 + reg;
                int col = wc * 32 + ct * 16 + r;
                pt[row * 64 + col] = acc[rt][ct][reg];
            }
}

// ---------------------------------------------------------------------------
// reduce partials -> a and z0, mirrored via LDS transpose
// ---------------------------------------------------------------------------
__global__ __launch_bounds__(256) void k_reduce(
    const float* __restrict__ part, const float* __restrict__ sbuf,
    const float* __restrict__ trbuf,
    unsigned short* __restrict__ Ahh, unsigned short* __restrict__ All,
    unsigned short* __restrict__ Zhh, unsigned short* __restrict__ Zll) {
    const int b = blockIdx.y;
    int p = blockIdx.x, tm = 0, rem = 4;
    while (p >= rem) { p -= rem; ++tm; --rem; }
    const int tn = tm + p;

    const float* pb = part + ((size_t)blockIdx.x * BATCH + b) * KSPLIT * 4096;
    const int t = threadIdx.x;
    const int row = t >> 2, c0 = (t & 3) * 16;

    float s[16];
#pragma unroll
    for (int u = 0; u < 16; ++u) s[u] = 0.f;
    for (int sp = 0; sp < KSPLIT; ++sp) {
        const float* q4 = pb + sp * 4096 + row * 64 + c0;
#pragma unroll
        for (int u4 = 0; u4 < 4; ++u4) {
            float4 v = *(const float4*)(q4 + u4 * 4);
            s[u4 * 4 + 0] += v.x; s[u4 * 4 + 1] += v.y;
            s[u4 * 4 + 2] += v.z; s[u4 * 4 + 3] += v.w;
        }
    }

    const float invn = 1.f / (float)HW, invn2 = invn * invn;
    const float tr = trbuf[b];
    const int gi = tm * 64 + row;
    const float si = sbuf[b * C + gi];
    const size_t mo = (size_t)b * C * C;

    __shared__ unsigned short tAh[64][66], tAl[64][66], tZh[64][66], tZl[64][66];
    unsigned short vAh[16], vAl[16], vZh[16], vZl[16];
#pragma unroll
    for (int u = 0; u < 16; ++u) {
        int gj = tn * 64 + c0 + u;
        float sj = sbuf[b * C + gj];
        float a = (s[u] * invn - si * sj * invn2) / tr;
        split2(a, vAh[u], vAl[u]);
        float zv = ((gi == gj) ? 1.5f : 0.f) - 0.5f * a;
        split2(zv, vZh[u], vZl[u]);
        tAh[row][c0 + u] = vAh[u]; tAl[row][c0 + u] = vAl[u];
        tZh[row][c0 + u] = vZh[u]; tZl[row][c0 + u] = vZl[u];
    }
    size_t off = mo + (size_t)gi * C + tn * 64 + c0;
#pragma unroll
    for (int u4 = 0; u4 < 4; ++u4) {
        *(ushort4*)&Ahh[off + u4 * 4] = *(ushort4*)&vAh[u4 * 4];
        *(ushort4*)&All[off + u4 * 4] = *(ushort4*)&vAl[u4 * 4];
        *(ushort4*)&Zhh[off + u4 * 4] = *(ushort4*)&vZh[u4 * 4];
        *(ushort4*)&Zll[off + u4 * 4] = *(ushort4*)&vZl[u4 * 4];
    }
    if (tm != tn) {
        __syncthreads();
        const int mr = t >> 2, mc0 = (t & 3) * 16;
        size_t moff = mo + (size_t)(tn * 64 + mr) * C + tm * 64 + mc0;
        unsigned short wAh[16], wAl[16], wZh[16], wZl[16];
#pragma unroll
        for (int u = 0; u < 16; ++u) {
            wAh[u] = tAh[mc0 + u][mr]; wAl[u] = tAl[mc0 + u][mr];
            wZh[u] = tZh[mc0 + u][mr]; wZl[u] = tZl[mc0 + u][mr];
        }
#pragma unroll
        for (int u4 = 0; u4 < 4; ++u4) {
            *(ushort4*)&Ahh[moff + u4 * 4] = *(ushort4*)&wAh[u4 * 4];
            *(ushort4*)&All[moff + u4 * 4] = *(ushort4*)&wAl[u4 * 4];
            *(ushort4*)&Zhh[moff + u4 * 4] = *(ushort4*)&wZh[u4 * 4];
            *(ushort4*)&Zll[moff + u4 * 4] = *(ushort4*)&wZl[u4 * 4];
        }
    }
}

// ---------------------------------------------------------------------------
// NS block GEMM core: 128x128 block tile, 4 waves (2x2) of 64x64, K=256,
// double-buffered global_load_lds staging, all operands symmetric (row reads).
// LDS per op: [c(4)][row(128)][8] = 4096 shorts.
// ---------------------------------------------------------------------------
__device__ __forceinline__ void block_gemm128(
    const unsigned short* __restrict__ Ah, const unsigned short* __restrict__ Al,
    const unsigned short* __restrict__ Bh, const unsigned short* __restrict__ Bl,
    int tm, int tn, unsigned short (*lds)[4][4096], f4v acc[4][4]) {
    const int tid = threadIdx.x, wave = tid >> 6, lane = tid & 63;
    const int wr = wave >> 1, wc = wave & 1;
    const int q = lane >> 4, r = lane & 15;

    const unsigned short* sb = (wave == 0) ? Ah : (wave == 1) ? Al
                             : (wave == 2) ? Bh : Bl;
    const int row0 = (wave < 2) ? tm * 128 : tn * 128;
    const unsigned short* g0 = sb + (size_t)(row0 + lane) * C;
    const unsigned short* g1 = g0 + (size_t)64 * C;

    // prologue stage into buf 0
#pragma unroll
    for (int c = 0; c < 4; ++c) {
        stage16(g0 + c * 8, &lds[0][wave][c * 1024]);
        stage16(g1 + c * 8, &lds[0][wave][c * 1024 + 512]);
    }

    for (int s = 0; s < 8; ++s) {
        const int cb = s & 1, nb = cb ^ 1;
        __syncthreads();
        if (s < 7) {
            const int k0 = (s + 1) * 32;
#pragma unroll
            for (int c = 0; c < 4; ++c) {
                stage16(g0 + k0 + c * 8, &lds[nb][wave][c * 1024]);
                stage16(g1 + k0 + c * 8, &lds[nb][wave][c * 1024 + 512]);
            }
        }
        b8v ah[4], al[4], bh[4], bl[4];
#pragma unroll
        for (int i = 0; i < 4; ++i) {
            const int ra = (wr * 64 + i * 16 + r) * 8 + q * 1024;
            ah[i] = *(const b8v*)&lds[cb][0][ra];
            al[i] = *(const b8v*)&lds[cb][1][ra];
            const int rb = (wc * 64 + i * 16 + r) * 8 + q * 1024;
            bh[i] = *(const b8v*)&lds[cb][2][rb];
            bl[i] = *(const b8v*)&lds[cb][3][rb];
        }
#pragma unroll
        for (int i = 0; i < 4; ++i)
#pragma unroll
            for (int j = 0; j < 4; ++j) {
                acc[i][j] = __builtin_amdgcn_mfma_f32_16x16x32_bf16(ah[i], bh[j], acc[i][j], 0, 0, 0);
                acc[i][j] = __builtin_amdgcn_mfma_f32_16x16x32_bf16(ah[i], bl[j], acc[i][j], 0, 0, 0);
                acc[i][j] = __builtin_amdgcn_mfma_f32_16x16x32_bf16(al[i], bh[j], acc[i][j], 0, 0, 0);
            }
    }
}

// MODE 0: D = acc ; MODE 1: D = 1.5I - 0.5 acc ; MODE 2: triuvec(acc*sqrt(tr))
template <int MODE>
__global__ __launch_bounds__(256) void k_g128(
    const unsigned short* __restrict__ Ah, const unsigned short* __restrict__ Al,
    const unsigned short* __restrict__ Bh, const unsigned short* __restrict__ Bl,
    unsigned short* __restrict__ Dh, unsigned short* __restrict__ Dl,
    float* __restrict__ outF, const float* __restrict__ strbuf) {
    const int b = blockIdx.y;
    int tm, tn;
    if (MODE == 2) {
        tm = (blockIdx.x == 2) ? 1 : 0;
        tn = (blockIdx.x >= 1) ? 1 : 0;
    } else {
        tm = blockIdx.x >> 1;
        tn = blockIdx.x & 1;
    }
    __shared__ __align__(16) unsigned short lds[2][4][4096];
    const size_t mo = (size_t)b * C * C;
    f4v acc[4][4] = {};
    block_gemm128(Ah + mo, Al + mo, Bh + mo, Bl + mo, tm, tn, lds, acc);

    const int lane = threadIdx.x & 63, wave = threadIdx.x >> 6;
    const int wr = wave >> 1, wc = wave & 1;
    const int q = lane >> 4, r = lane & 15;

    if (MODE == 2) {
        const float sc = strbuf[b];
#pragma unroll
        for (int i = 0; i < 4; ++i)
#pragma unroll
            for (int j = 0; j < 4; ++j) {
                const int gj = tn * 128 + wc * 64 + j * 16 + r;
#pragma unroll
                for (int reg = 0; reg < 4; ++reg) {
                    const int gi = tm * 128 + wr * 64 + i * 16 + q * 4 + reg;
                    if (gj >= gi)
                        outF[(size_t)b * OUTROW + (size_t)(gi * C - (gi * (gi - 1)) / 2) +
                             (gj - gi)] = acc[i][j][reg] * sc;
                }
            }
    } else {
#pragma unroll
        for (int i = 0; i < 4; ++i)
#pragma unroll
            for (int j = 0; j < 4; ++j) {
                const int gj = tn * 128 + wc * 64 + j * 16 + r;
#pragma unroll
                for (int reg = 0; reg < 4; ++reg) {
                    const int gi = tm * 128 + wr * 64 + i * 16 + q * 4 + reg;
                    float v = acc[i][j][reg];
                    if (MODE == 1) v = ((gi == gj) ? 1.5f : 0.f) - 0.5f * v;
                    unsigned short h, l;
                    split2(v, h, l);
                    Dh[mo + (size_t)gi * C + gj] = h;
                    Dl[mo + (size_t)gi * C + gj] = l;
                }
            }
    }
}

// fused Ynew = Y@T (z=0), Znew = T@Z (z=1)
__global__ __launch_bounds__(256) void k_yz128(
    const unsigned short* __restrict__ Yh, const unsigned short* __restrict__ Yl,
    const unsigned short* __restrict__ Th, const unsigned short* __restrict__ Tl,
    const unsigned short* __restrict__ Zh, const unsigned short* __restrict__ Zl,
    unsigned short* __restrict__ Ynh, unsigned short* __restrict__ Ynl,
    unsigned short* __restrict__ Znh, unsigned short* __restrict__ Znl) {
    const int b = blockIdx.y, zz = blockIdx.z;
    const int tm = blockIdx.x >> 1, tn = blockIdx.x & 1;
    const unsigned short* Ah = zz ? Th : Yh;
    const unsigned short* Al = zz ? Tl : Yl;
    const unsigned short* Bh = zz ? Zh : Th;
    const unsigned short* Bl = zz ? Zl : Tl;
    unsigned short* Dh = zz ? Znh : Ynh;
    unsigned short* Dl = zz ? Znl : Ynl;

    __shared__ __align__(16) unsigned short lds[2][4][4096];
    const size_t mo = (size_t)b * C * C;
    f4v acc[4][4] = {};
    block_gemm128(Ah + mo, Al + mo, Bh + mo, Bl + mo, tm, tn, lds, acc);

    const int lane = threadIdx.x & 63, wave = threadIdx.x >> 6;
    const int wr = wave >> 1, wc = wave & 1;
    const int q = lane >> 4, r = lane & 15;
#pragma unroll
    for (int i = 0; i < 4; ++i)
#pragma unroll
        for (int j = 0; j < 4; ++j) {
            const int gj = tn * 128 + wc * 64 + j * 16 + r;
#pragma unroll
            for (int reg = 0; reg < 4; ++reg) {
                const int gi = tm * 128 + wr * 64 + i * 16 + q * 4 + reg;
                unsigned short h, l;
                split2(acc[i][j][reg], h, l);
                Dh[mo + (size_t)gi * C + gj] = h;
                Dl[mo + (size_t)gi * C + gj] = l;
            }
        }
}

// ---------------------------------------------------------------------------
extern "C" void kernel_launch(void* const* d_in, const int* in_sizes, int n_in,
                              void* d_out, int out_size, void* d_ws, size_t ws_size,
                              hipStream_t stream) {
    const float* x = (const float*)d_in[0];
    float* out = (float*)d_out;

    unsigned short* W = (unsigned short*)d_ws;
    const size_t XN = (size_t)BATCH * C * HW;
    const size_t M = (size_t)BATCH * C * C;
    unsigned short* XH = W;
    unsigned short* XL = XH + XN;
    float* sbuf = (float*)(XL + XN);
    float* qbuf = sbuf + BATCH * C;
    float* trbuf = qbuf + BATCH * C;
    float* strbuf = trbuf + BATCH;
    unsigned short* P = (unsigned short*)(strbuf + BATCH);
    unsigned short* PA_h = P + 0 * M; unsigned short* PA_l = P + 1 * M;
    unsigned short* PB_h = P + 2 * M; unsigned short* PB_l = P + 3 * M;
    unsigned short* PC_h = P + 4 * M; unsigned short* PC_l = P + 5 * M;
    unsigned short* PD_h = P + 6 * M; unsigned short* PD_l = P + 7 * M;
    unsigned short* PE_h = P + 8 * M; unsigned short* PE_l = P + 9 * M;
    // fp32 partials alias PC..PE + beyond (dead until Y0 is written)
    float* part = (float*)PC_h;   // 10*32*7*4096 floats

    k_prep<<<dim3(BATCH * C), 256, 0, stream>>>(x, XH, XL, sbuf, qbuf);
    k_tr<<<dim3(BATCH), 256, 0, stream>>>(sbuf, qbuf, trbuf, strbuf);
    k_gram_split<<<dim3(10 * BATCH * KSPLIT), 256, 0, stream>>>(XH, XL, part);
    k_reduce<<<dim3(10, BATCH), 256, 0, stream>>>(part, sbuf, trbuf,
                                                  PA_h, PA_l, PB_h, PB_l);

    dim3 g4(4, BATCH);
    // Y0 = a @ z0 -> PC
    k_g128<0><<<g4, 256, 0, stream>>>(PA_h, PA_l, PB_h, PB_l, PC_h, PC_l, nullptr, strbuf);
    // it0: T0 = 1.5I - 0.5 Z0@Y0 = PB@PC -> PD ; Y1 = PC@PD -> PA ; Z1 = PD@PB -> PE
    k_g128<1><<<g4, 256, 0, stream>>>(PB_h, PB_l, PC_h, PC_l, PD_h, PD_l, nullptr, strbuf);
    k_yz128<<<dim3(4, BATCH, 2), 256, 0, stream>>>(PC_h, PC_l, PD_h, PD_l, PB_h, PB_l,
                                                   PA_h, PA_l, PE_h, PE_l);
    // it1: T1 = PE@PA -> PB ; Y2 = PA@PB -> PC ; Z2 = PB@PE -> PD
    k_g128<1><<<g4, 256, 0, stream>>>(PE_h, PE_l, PA_h, PA_l, PB_h, PB_l, nullptr, strbuf);
    k_yz128<<<dim3(4, BATCH, 2), 256, 0, stream>>>(PA_h, PA_l, PB_h, PB_l, PE_h, PE_l,
                                                   PC_h, PC_l, PD_h, PD_l);
    // it2: T2 = PD@PC -> PA ; Y3 = PC@PA -> PB ; Z3 = PA@PD -> PE
    k_g128<1><<<g4, 256, 0, stream>>>(PD_h, PD_l, PC_h, PC_l, PA_h, PA_l, nullptr, strbuf);
    k_yz128<<<dim3(4, BATCH, 2), 256, 0, stream>>>(PC_h, PC_l, PA_h, PA_l, PD_h, PD_l,
                                                   PB_h, PB_l, PE_h, PE_l);
    // it3: T3 = PE@PB -> PC ; out = triuvec((PB@PC) * sqrt(tr))
    k_g128<1><<<g4, 256, 0, stream>>>(PE_h, PE_l, PB_h, PB_l, PC_h, PC_l, nullptr, strbuf);
    k_g128<2><<<dim3(3, BATCH), 256, 0, stream>>>(PB_h, PB_l, PC_h, PC_l, nullptr, nullptr,
                                                  out, strbuf);
}